// Round 10
// baseline (187.230 us; speedup 1.0000x reference)
//
#include <hip/hip_runtime.h>
#include <hip/hip_bf16.h>
#include <math.h>

#define NHEADS 16
#define HDIM   64
#define BATCH  2
#define SEQLEN 2048
#define DIMSZ  1024

typedef _Float16 f16x8 __attribute__((ext_vector_type(8)));
typedef float    f32x4 __attribute__((ext_vector_type(4)));
typedef unsigned short u16x8 __attribute__((ext_vector_type(8)));
typedef unsigned int   u32x4 __attribute__((ext_vector_type(4)));

__device__ __forceinline__ float rope_theta(int c) {
    int i = c & 31;
    return (float)pow(10000.0, -(double)i / 32.0);
}
__device__ __forceinline__ unsigned short f16u(float f) {
    _Float16 h = (_Float16)f;
    return *reinterpret_cast<unsigned short*>(&h);
}
__device__ __forceinline__ void async_copy16(const void* gsrc, void* lds) {
    __builtin_amdgcn_global_load_lds(
        (const __attribute__((address_space(1))) unsigned int*)gsrc,
        (__attribute__((address_space(3))) unsigned int*)lds, 16, 0, 0);
}

// ---------------------------------------------------------------------------
// prep: f32->f16 conversions (x, Wq|Wk|Wv concat, Wo), bias concat, rope tables
// ---------------------------------------------------------------------------
__global__ __launch_bounds__(256) void prep_kernel(
    const float* __restrict__ x, const float* __restrict__ Wq,
    const float* __restrict__ Wk, const float* __restrict__ Wv,
    const float* __restrict__ Wo, const float* __restrict__ bq,
    const float* __restrict__ bk, const float* __restrict__ bv,
    unsigned short* __restrict__ x16, unsigned short* __restrict__ Wqkv16,
    unsigned short* __restrict__ Wo16, float* __restrict__ biasqkv,
    float* __restrict__ ropeC, float* __restrict__ ropeS)
{
    const int NV = (4194304 + 4 * 1048576) / 8;   // 1,048,576 vec8 chunks
    int gid = blockIdx.x * 256 + threadIdx.x;
    for (int i = gid; i < NV; i += gridDim.x * 256) {
        long e = (long)i * 8;
        const float* src; unsigned short* dst; long off;
        if (e < 4194304)      { src = x;  dst = x16;              off = e; }
        else if (e < 5242880) { src = Wq; dst = Wqkv16;           off = e - 4194304; }
        else if (e < 6291456) { src = Wk; dst = Wqkv16 + 1048576; off = e - 5242880; }
        else if (e < 7340032) { src = Wv; dst = Wqkv16 + 2097152; off = e - 6291456; }
        else                  { src = Wo; dst = Wo16;             off = e - 7340032; }
        float4 v0 = *reinterpret_cast<const float4*>(src + off);
        float4 v1 = *reinterpret_cast<const float4*>(src + off + 4);
        u16x8 o;
        o[0] = f16u(v0.x); o[1] = f16u(v0.y); o[2] = f16u(v0.z); o[3] = f16u(v0.w);
        o[4] = f16u(v1.x); o[5] = f16u(v1.y); o[6] = f16u(v1.z); o[7] = f16u(v1.w);
        *reinterpret_cast<u16x8*>(dst + off) = o;
    }
    if (gid < 65536) {
        int npos = gid >> 5, j = gid & 31;
        float f = (float)npos * rope_theta(j);
        ropeC[gid] = cosf(f);
        ropeS[gid] = sinf(f);
    }
    if (gid < 3072) {
        biasqkv[gid] = gid < 1024 ? bq[gid] : (gid < 2048 ? bk[gid - 1024] : bv[gid - 2048]);
    }
}

// ---------------------------------------------------------------------------
// Fused QKV GEMM + bias + (non-standard) rope.
//   Q, K -> (b,h,n,d) f16;  V -> TRANSPOSED (b,h,d,n) f16 via LDS transpose.
//   out[p]    = x[2p]*rope[2p]   - x[2p+1]*rope[2p+1]
//   out[p+32] = x[2p]*rope[2p+1] + x[2p+1]*rope[2p]
// ---------------------------------------------------------------------------
__global__ __launch_bounds__(256) void qkv_gemm_kernel(
    const unsigned short* __restrict__ A, const unsigned short* __restrict__ B,
    const float* __restrict__ bias, const float* __restrict__ ropeC,
    const float* __restrict__ ropeS, unsigned short* __restrict__ QKV)
{
    __shared__ __align__(16) unsigned char smem[34816];   // max(As+Bs 32768, T 34816)
    _Float16 (*As)[64] = (_Float16(*)[64])smem;            // [128][64]
    _Float16 (*Bs)[64] = (_Float16(*)[64])(smem + 16384);  // [128][64]
    const int tid = threadIdx.x;
    const int w = tid >> 6, lane = tid & 63;
    const int g = lane >> 4, lx = lane & 15;
    const int wr = w >> 1, wc = w & 1;
    const int row0 = blockIdx.y * 128;
    const int col0 = blockIdx.x * 128;
    const unsigned short* Ab = A + (size_t)row0 * DIMSZ;
    const unsigned short* Bb = B + (size_t)col0 * DIMSZ;

    f32x4 acc[4][4] = {};
    for (int k0 = 0; k0 < DIMSZ; k0 += 64) {
        __syncthreads();
        #pragma unroll
        for (int i = 0; i < 4; ++i) {
            int idx = i * 256 + tid;
            int r = idx >> 3, cb = (idx & 7) * 8;
            async_copy16(Ab + (size_t)r * DIMSZ + k0 + cb,
                         (_Float16*)As + (size_t)(i * 256 + w * 64) * 8);
        }
        #pragma unroll
        for (int i = 0; i < 4; ++i) {
            int idx = i * 256 + tid;
            int r = idx >> 3, cb = (idx & 7) * 8;
            async_copy16(Bb + (size_t)r * DIMSZ + k0 + cb,
                         (_Float16*)Bs + (size_t)(i * 256 + w * 64) * 8);
        }
        __syncthreads();
        #pragma unroll
        for (int ks = 0; ks < 2; ++ks) {
            f16x8 af[4], bf[4];
            #pragma unroll
            for (int m = 0; m < 4; ++m)
                af[m] = *reinterpret_cast<const f16x8*>(&As[wr * 64 + m * 16 + lx][ks * 32 + g * 8]);
            #pragma unroll
            for (int n = 0; n < 4; ++n)
                bf[n] = *reinterpret_cast<const f16x8*>(&Bs[wc * 64 + n * 16 + lx][ks * 32 + g * 8]);
            #pragma unroll
            for (int m = 0; m < 4; ++m)
                #pragma unroll
                for (int n = 0; n < 4; ++n)
                    acc[m][n] = __builtin_amdgcn_mfma_f32_16x16x32_f16(af[m], bf[n], acc[m][n], 0, 0, 0);
        }
    }

    const int hcol0 = col0 + wc * 64;          // multiple of 64, one head
    const int proj  = hcol0 >> 10;
    const int hd    = (hcol0 & 1023) >> 6;
    float bsv[4];
    #pragma unroll
    for (int n = 0; n < 4; ++n) bsv[n] = bias[hcol0 + n * 16 + lx];

    if (proj == 2) {
        // ---- V: rope -> LDS transpose T[d][rlocal] -> coalesced (b,h,d,n) stores
        __syncthreads();
        _Float16* T = (_Float16*)smem;   // [128][136] = 34816B
        #pragma unroll
        for (int m = 0; m < 4; ++m) {
            int rl0 = wr * 64 + m * 16 + g * 4;
            #pragma unroll
            for (int r2 = 0; r2 < 4; ++r2) {
                int rlocal = rl0 + r2;
                int npos = (row0 + rlocal) & (SEQLEN - 1);
                const float* rcp = ropeC + npos * 32;
                const float* rsp = ropeS + npos * 32;
                #pragma unroll
                for (int n = 0; n < 4; ++n) {
                    float v = acc[m][n][r2] + bsv[n];
                    float o = __shfl_xor(v, 1);
                    int d = n * 16 + lx;
                    const float* tab = (d < 32) ? rcp : rsp;
                    float Rd = tab[d & 31];
                    float Rp = tab[(d & 31) ^ 1];
                    float y; int outc;
                    if (d & 1) { y = o * Rd + v * Rp; outc = (d >> 1) + 32; }
                    else       { y = v * Rd - o * Rp; outc = d >> 1; }
                    T[(wc * 64 + outc) * 136 + rlocal] = (_Float16)y;
                }
            }
        }
        __syncthreads();
        int b = row0 >> 11, npos0 = row0 & (SEQLEN - 1);
        int hd0 = (col0 & 1023) >> 6;
        #pragma unroll
        for (int i2 = 0; i2 < 8; ++i2) {
            int trow = w * 32 + i2 * 4 + g;
            int head = hd0 + (trow >> 6);
            int outd = trow & 63;
            f16x8 val = *reinterpret_cast<const f16x8*>(&T[trow * 136 + lx * 8]);
            *reinterpret_cast<f16x8*>(QKV + 8388608 +
                (((size_t)b * NHEADS + head) * HDIM + outd) * SEQLEN + npos0 + lx * 8) = val;
        }
    } else {
        #pragma unroll
        for (int m = 0; m < 4; ++m) {
            int rbase = row0 + wr * 64 + m * 16 + g * 4;
            #pragma unroll
            for (int r2 = 0; r2 < 4; ++r2) {
                int rglob = rbase + r2;
                int b = rglob >> 11, npos = rglob & (SEQLEN - 1);
                const float* rcp = ropeC + npos * 32;
                const float* rsp = ropeS + npos * 32;
                unsigned short* Orow = QKV +
                    ((((size_t)proj * BATCH + b) * NHEADS + hd) * SEQLEN + npos) * HDIM;
                #pragma unroll
                for (int n = 0; n < 4; ++n) {
                    float v = acc[m][n][r2] + bsv[n];   // x[d], d = n*16+lx
                    float o = __shfl_xor(v, 1);         // x[d^1]
                    int d = n * 16 + lx;
                    const float* tab = (d < 32) ? rcp : rsp;
                    float Rd = tab[d & 31];             // rope[d]
                    float Rp = tab[(d & 31) ^ 1];       // rope[d^1]
                    float y; int outc;
                    if (d & 1) { y = o * Rd + v * Rp; outc = (d >> 1) + 32; }
                    else       { y = v * Rd - o * Rp; outc = d >> 1; }
                    Orow[outc] = f16u(y);
                }
            }
        }
    }
}

// ---------------------------------------------------------------------------
// MFMA flash attention (f16), SWAPPED-QK^T form: S^T = mfma(K, Q) so each
// lane owns one q-column (q = lane&15). Max-reduce = 2 shfl; P stays in
// registers (cvt_pkrtz + 4-lane-group shfl redistribution, no LDS round trip).
// PV: O^T = mfma(V^T, P); lsum via mfma(ones, P). Epilogue rope lane-local.
// LDS: K @0 (8KB) | V^T @8192 (8KB). XCD-aware flat grid.
// ---------------------------------------------------------------------------
__global__ __launch_bounds__(256) void attn_mfma_kernel(
    const unsigned short* __restrict__ QKV, const float* __restrict__ ropeC,
    const float* __restrict__ ropeS, unsigned short* __restrict__ Y)
{
    __shared__ __align__(16) unsigned char smem[16384];
    const int tid = threadIdx.x;
    const int w   = tid >> 6;
    const int l   = tid & 63;
    const int g   = l >> 4;
    const int lx  = l & 15;
    const int r8  = l >> 3;     // 0..7
    const int c8  = l & 7;      // chunk slot within row
    const int fb  = blockIdx.x;
    const int xcd = fb & 7, jj = fb >> 3;
    const int bh  = xcd * 4 + (jj & 3);       // 4 bh per XCD -> K/V L2-local
    const int b   = bh >> 4;
    const int h   = bh & 15;
    const int q0  = (jj >> 2) * 64;

    const unsigned short* Qb  = QKV + (size_t)bh * SEQLEN * HDIM;
    const unsigned short* Kb  = QKV + 4194304 + (size_t)bh * SEQLEN * HDIM;
    const unsigned short* Vtb = QKV + 8388608 + (size_t)bh * SEQLEN * HDIM;  // (d,n)

    f16x8 qf[2];
    {
        const unsigned short* src = Qb + (size_t)(q0 + w * 16 + lx) * HDIM + g * 8;
        qf[0] = *reinterpret_cast<const f16x8*>(src);
        qf[1] = *reinterpret_cast<const f16x8*>(src + 32);
    }
    f16x8 ones;
    #pragma unroll
    for (int i = 0; i < 8; ++i) ones[i] = (_Float16)1.0f;

    const float K2 = 0.18033688011112043f;    // 0.125 * log2(e)
    f32x4 oacc[4] = {};                        // O^T: d = c*16+g*4+r, q = lx
    f32x4 lsum = {};
    float mrow = -1e30f;                       // per-lane: one q
    const int srcA = lx + ((l & 16) << 1);     // lx + 32*(g&1)
    const int srcB = srcA + 16;
    const bool hi = (l >= 32);                 // g>>1

    for (int kt = 0; kt < SEQLEN / 64; ++kt) {
        const int k0 = kt * 64;
        __syncthreads();   // prev tile's reads done
        // ---- stage K and V^T: linear LDS dest, inverse-swizzled global src
        #pragma unroll
        for (int p = 0; p < 2; ++p) {
            int row = p * 32 + w * 8 + r8;          // key (K) / d (V^T)
            int ch  = c8 ^ (row & 7);
            async_copy16(Kb  + (size_t)(k0 + row) * HDIM + ch * 8,
                         smem + p * 4096 + w * 1024);
            async_copy16(Vtb + (size_t)row * SEQLEN + k0 + ch * 8,
                         smem + 8192 + p * 4096 + w * 1024);
        }
        __syncthreads();   // staged

        // ---- swapped QK^T: sacc[c] = S^T[key = c*16+g*4+r][q = lx]
        f32x4 sacc[4] = {};
        #pragma unroll
        for (int c = 0; c < 4; ++c) {
            int key = c * 16 + lx;
            int rowb = key * 128, sw = (key & 7) << 4;
            f16x8 k0f = *reinterpret_cast<const f16x8*>(&smem[rowb + ((g * 16) ^ sw)]);
            f16x8 k1f = *reinterpret_cast<const f16x8*>(&smem[rowb + ((64 + g * 16) ^ sw)]);
            sacc[c] = __builtin_amdgcn_mfma_f32_16x16x32_f16(k0f, qf[0], sacc[c], 0, 0, 0);
            sacc[c] = __builtin_amdgcn_mfma_f32_16x16x32_f16(k1f, qf[1], sacc[c], 0, 0, 0);
        }

        // ---- softmax, deferred max (THR = 64 raw = 8 post-scale)
        float lmax = sacc[0][0];
        #pragma unroll
        for (int c = 0; c < 4; ++c)
            #pragma unroll
            for (int r = 0; r < 4; ++r) lmax = fmaxf(lmax, sacc[c][r]);
        bool ok = (lmax <= mrow + 64.f);
        if (!__all((int)ok)) {
            float m2 = fmaxf(lmax, __shfl_xor(lmax, 16));
            m2 = fmaxf(m2, __shfl_xor(m2, 32));
            float mnew = fmaxf(mrow, m2);
            float sc = exp2f((mrow - mnew) * K2);
            mrow = mnew;
            #pragma unroll
            for (int r = 0; r < 4; ++r) lsum[r] *= sc;
            #pragma unroll
            for (int c = 0; c < 4; ++c)
                #pragma unroll
                for (int r = 0; r < 4; ++r) oacc[c][r] *= sc;
        }
        float mk = -mrow * K2;
        #pragma unroll
        for (int c = 0; c < 4; ++c)
            #pragma unroll
            for (int r = 0; r < 4; ++r)
                sacc[c][r] = exp2f(fmaf(sacc[c][r], K2, mk));

        // ---- pack P to f16 pairs: pk[c][rr] = keys (c*16+g*4+2rr, +1), q=lx
        unsigned pk[4][2];
        #pragma unroll
        for (int c = 0; c < 4; ++c)
            #pragma unroll
            for (int rr = 0; rr < 2; ++rr) {
                auto hpair = __builtin_amdgcn_cvt_pkrtz(sacc[c][2 * rr], sacc[c][2 * rr + 1]);
                pk[c][rr] = __builtin_bit_cast(unsigned, hpair);
            }

        // ---- redistribute P^T to B-frag layout + PV (+ ones row-sum)
        #pragma unroll
        for (int kc = 0; kc < 2; ++kc) {
            unsigned w0a = __shfl((int)pk[2 * kc][0], srcA), w0b = __shfl((int)pk[2 * kc + 1][0], srcA);
            unsigned w1a = __shfl((int)pk[2 * kc][1], srcA), w1b = __shfl((int)pk[2 * kc + 1][1], srcA);
            unsigned w2a = __shfl((int)pk[2 * kc][0], srcB), w2b = __shfl((int)pk[2 * kc + 1][0], srcB);
            unsigned w3a = __shfl((int)pk[2 * kc][1], srcB), w3b = __shfl((int)pk[2 * kc + 1][1], srcB);
            u32x4 tw = { hi ? w0b : w0a, hi ? w1b : w1a, hi ? w2b : w2a, hi ? w3b : w3a };
            f16x8 pfrag = __builtin_bit_cast(f16x8, tw);
            #pragma unroll
            for (int c = 0; c < 4; ++c) {
                int d = c * 16 + lx;
                f16x8 vf = *reinterpret_cast<const f16x8*>(
                    &smem[8192 + d * 128 + ((kc * 64 + g * 16) ^ ((d & 7) << 4))]);
                oacc[c] = __builtin_amdgcn_mfma_f32_16x16x32_f16(vf, pfrag, oacc[c], 0, 0, 0);
            }
            lsum = __builtin_amdgcn_mfma_f32_16x16x32_f16(ones, pfrag, lsum, 0, 0, 0);
        }
    }

    // ---- epilogue: normalize, -rope (lane-local pairs), packed dword stores
    float inv = 1.0f / lsum[0];
    const int q = q0 + w * 16 + lx;
    unsigned short* drow = Y + ((size_t)b * SEQLEN + q) * DIMSZ + h * HDIM;
    #pragma unroll
    for (int c = 0; c < 4; ++c) {
        const float* tab = ((c < 2) ? ropeC : ropeS) + (size_t)q * 32;
        unsigned short lo16[2], hi16[2];
        #pragma unroll
        for (int rp = 0; rp < 2; ++rp) {
            int d = c * 16 + g * 4 + 2 * rp;        // even d
            float v0 = oacc[c][2 * rp] * inv;
            float v1 = oacc[c][2 * rp + 1] * inv;
            float Rd = tab[d & 31], Rn = tab[(d & 31) + 1];
            lo16[rp] = f16u(-(v0 * Rd - v1 * Rn));
            hi16[rp] = f16u(-(v0 * Rn + v1 * Rd));
        }
        int p = c * 8 + g * 2;                       // even column
        *reinterpret_cast<unsigned*>(&drow[p])      = (unsigned)lo16[0] | ((unsigned)lo16[1] << 16);
        *reinterpret_cast<unsigned*>(&drow[p + 32]) = (unsigned)hi16[0] | ((unsigned)hi16[1] << 16);
    }
}

// ---------------------------------------------------------------------------
// Out GEMM: out[4096 x 1024] = Y16 @ Wo16^T + bo (f32 out)
// ---------------------------------------------------------------------------
__global__ __launch_bounds__(256) void out_gemm_kernel(
    const unsigned short* __restrict__ A, const unsigned short* __restrict__ B,
    const float* __restrict__ bias, float* __restrict__ Out)
{
    __shared__ __align__(16) _Float16 As[128][64];
    __shared__ __align__(16) _Float16 Bs[128][64];
    const int tid = threadIdx.x;
    const int w = tid >> 6, lane = tid & 63;
    const int g = lane >> 4, lx = lane & 15;
    const int wr = w >> 1, wc = w & 1;
    const int row0 = blockIdx.y * 128;
    const int col0 = blockIdx.x * 128;
    const unsigned short* Ab = A + (size_t)row0 * DIMSZ;
    const unsigned short* Bb = B + (size_t)col0 * DIMSZ;

    f32x4 acc[4][4] = {};
    for (int k0 = 0; k0 < DIMSZ; k0 += 64) {
        __syncthreads();
        #pragma unroll
        for (int i = 0; i < 4; ++i) {
            int idx = i * 256 + tid;
            int r = idx >> 3, cb = (idx & 7) * 8;
            async_copy16(Ab + (size_t)r * DIMSZ + k0 + cb,
                         (_Float16*)As + (size_t)(i * 256 + w * 64) * 8);
        }
        #pragma unroll
        for (int i = 0; i < 4; ++i) {
            int idx = i * 256 + tid;
            int r = idx >> 3, cb = (idx & 7) * 8;
            async_copy16(Bb + (size_t)r * DIMSZ + k0 + cb,
                         (_Float16*)Bs + (size_t)(i * 256 + w * 64) * 8);
        }
        __syncthreads();
        #pragma unroll
        for (int ks = 0; ks < 2; ++ks) {
            f16x8 af[4], bf[4];
            #pragma unroll
            for (int m = 0; m < 4; ++m)
                af[m] = *reinterpret_cast<const f16x8*>(&As[wr * 64 + m * 16 + lx][ks * 32 + g * 8]);
            #pragma unroll
            for (int n = 0; n < 4; ++n)
                bf[n] = *reinterpret_cast<const f16x8*>(&Bs[wc * 64 + n * 16 + lx][ks * 32 + g * 8]);
            #pragma unroll
            for (int m = 0; m < 4; ++m)
                #pragma unroll
                for (int n = 0; n < 4; ++n)
                    acc[m][n] = __builtin_amdgcn_mfma_f32_16x16x32_f16(af[m], bf[n], acc[m][n], 0, 0, 0);
        }
    }

    const int cb0 = col0 + wc * 64;
    float bsv[4];
    #pragma unroll
    for (int n = 0; n < 4; ++n) bsv[n] = bias[cb0 + n * 16 + lx];
    #pragma unroll
    for (int m = 0; m < 4; ++m) {
        int rbase = row0 + wr * 64 + m * 16 + g * 4;
        #pragma unroll
        for (int r2 = 0; r2 < 4; ++r2) {
            float* orow = Out + (size_t)(rbase + r2) * DIMSZ + cb0;
            #pragma unroll
            for (int n = 0; n < 4; ++n)
                orow[n * 16 + lx] = acc[m][n][r2] + bsv[n];
        }
    }
}

extern "C" void kernel_launch(void* const* d_in, const int* in_sizes, int n_in,
                              void* d_out, int out_size, void* d_ws, size_t ws_size,
                              hipStream_t stream) {
    const float* x  = (const float*)d_in[0];
    const float* Wq = (const float*)d_in[1];
    const float* bq = (const float*)d_in[2];
    const float* Wk = (const float*)d_in[3];
    const float* bk = (const float*)d_in[4];
    const float* Wv = (const float*)d_in[5];
    const float* bv = (const float*)d_in[6];
    const float* Wo = (const float*)d_in[7];
    const float* bo = (const float*)d_in[8];
    float* out = (float*)d_out;

    char* ws = (char*)d_ws;
    unsigned short* x16    = (unsigned short*)(ws);
    unsigned short* Wqkv16 = (unsigned short*)(ws + 8388608);
    unsigned short* Wo16   = (unsigned short*)(ws + 14680064);
    float* biasqkv         = (float*)(ws + 16777216);
    float* ropeC           = (float*)(ws + 16793600);
    float* ropeS           = (float*)(ws + 17055744);
    unsigned short* QKVw   = (unsigned short*)(ws + 17825792);
    unsigned short* Yw     = (unsigned short*)(ws + 42991616);

    dim3 blk(256);
    prep_kernel<<<dim3(2048), blk, 0, stream>>>(x, Wq, Wk, Wv, Wo, bq, bk, bv,
                                                x16, Wqkv16, Wo16, biasqkv, ropeC, ropeS);
    qkv_gemm_kernel<<<dim3(24, 32), blk, 0, stream>>>(x16, Wqkv16, biasqkv, ropeC, ropeS, QKVw);
    attn_mfma_kernel<<<dim3(1024), blk, 0, stream>>>(QKVw, ropeC, ropeS, Yw);
    out_gemm_kernel<<<dim3(8, 32), blk, 0, stream>>>(Yw, Wo16, bo, out);
}

// Round 11
// 182.823 us; speedup vs baseline: 1.0241x; 1.0241x over previous
//
#include <hip/hip_runtime.h>
#include <hip/hip_bf16.h>
#include <math.h>

#define NHEADS 16
#define HDIM   64
#define BATCH  2
#define SEQLEN 2048
#define DIMSZ  1024

typedef _Float16 f16x8 __attribute__((ext_vector_type(8)));
typedef _Float16 f16x4 __attribute__((ext_vector_type(4)));
typedef float    f32x4 __attribute__((ext_vector_type(4)));
typedef unsigned short u16x8 __attribute__((ext_vector_type(8)));
typedef unsigned int   u32x2 __attribute__((ext_vector_type(2)));

__device__ __forceinline__ float rope_theta(int c) {
    int i = c & 31;
    return (float)pow(10000.0, -(double)i / 32.0);
}
__device__ __forceinline__ unsigned short f16u(float f) {
    _Float16 h = (_Float16)f;
    return *reinterpret_cast<unsigned short*>(&h);
}
__device__ __forceinline__ void async_copy16(const void* gsrc, void* lds) {
    __builtin_amdgcn_global_load_lds(
        (const __attribute__((address_space(1))) unsigned int*)gsrc,
        (__attribute__((address_space(3))) unsigned int*)lds, 16, 0, 0);
}

// ---------------------------------------------------------------------------
// prep: f32->f16 conversions (x, Wq|Wk|Wv concat, Wo), bias concat, rope tables
// ---------------------------------------------------------------------------
__global__ __launch_bounds__(256) void prep_kernel(
    const float* __restrict__ x, const float* __restrict__ Wq,
    const float* __restrict__ Wk, const float* __restrict__ Wv,
    const float* __restrict__ Wo, const float* __restrict__ bq,
    const float* __restrict__ bk, const float* __restrict__ bv,
    unsigned short* __restrict__ x16, unsigned short* __restrict__ Wqkv16,
    unsigned short* __restrict__ Wo16, float* __restrict__ biasqkv,
    float* __restrict__ ropeC, float* __restrict__ ropeS)
{
    const int NV = (4194304 + 4 * 1048576) / 8;   // 1,048,576 vec8 chunks
    int gid = blockIdx.x * 256 + threadIdx.x;
    for (int i = gid; i < NV; i += gridDim.x * 256) {
        long e = (long)i * 8;
        const float* src; unsigned short* dst; long off;
        if (e < 4194304)      { src = x;  dst = x16;              off = e; }
        else if (e < 5242880) { src = Wq; dst = Wqkv16;           off = e - 4194304; }
        else if (e < 6291456) { src = Wk; dst = Wqkv16 + 1048576; off = e - 5242880; }
        else if (e < 7340032) { src = Wv; dst = Wqkv16 + 2097152; off = e - 6291456; }
        else                  { src = Wo; dst = Wo16;             off = e - 7340032; }
        float4 v0 = *reinterpret_cast<const float4*>(src + off);
        float4 v1 = *reinterpret_cast<const float4*>(src + off + 4);
        u16x8 o;
        o[0] = f16u(v0.x); o[1] = f16u(v0.y); o[2] = f16u(v0.z); o[3] = f16u(v0.w);
        o[4] = f16u(v1.x); o[5] = f16u(v1.y); o[6] = f16u(v1.z); o[7] = f16u(v1.w);
        *reinterpret_cast<u16x8*>(dst + off) = o;
    }
    if (gid < 65536) {
        int npos = gid >> 5, j = gid & 31;
        float f = (float)npos * rope_theta(j);
        ropeC[gid] = cosf(f);
        ropeS[gid] = sinf(f);
    }
    if (gid < 3072) {
        biasqkv[gid] = gid < 1024 ? bq[gid] : (gid < 2048 ? bk[gid - 1024] : bv[gid - 2048]);
    }
}

// ---------------------------------------------------------------------------
// Fused QKV GEMM + bias + (non-standard) rope.
//   Q, K -> (b,h,n,d) f16;  V -> TRANSPOSED (b,h,d,n) f16 via LDS transpose.
//   out[p]    = x[2p]*rope[2p]   - x[2p+1]*rope[2p+1]
//   out[p+32] = x[2p]*rope[2p+1] + x[2p+1]*rope[2p]
// ---------------------------------------------------------------------------
__global__ __launch_bounds__(256) void qkv_gemm_kernel(
    const unsigned short* __restrict__ A, const unsigned short* __restrict__ B,
    const float* __restrict__ bias, const float* __restrict__ ropeC,
    const float* __restrict__ ropeS, unsigned short* __restrict__ QKV)
{
    __shared__ __align__(16) unsigned char smem[34816];   // max(As+Bs 32768, T 34816)
    _Float16 (*As)[64] = (_Float16(*)[64])smem;            // [128][64]
    _Float16 (*Bs)[64] = (_Float16(*)[64])(smem + 16384);  // [128][64]
    const int tid = threadIdx.x;
    const int w = tid >> 6, lane = tid & 63;
    const int g = lane >> 4, lx = lane & 15;
    const int wr = w >> 1, wc = w & 1;
    const int row0 = blockIdx.y * 128;
    const int col0 = blockIdx.x * 128;
    const unsigned short* Ab = A + (size_t)row0 * DIMSZ;
    const unsigned short* Bb = B + (size_t)col0 * DIMSZ;

    f32x4 acc[4][4] = {};
    for (int k0 = 0; k0 < DIMSZ; k0 += 64) {
        __syncthreads();
        #pragma unroll
        for (int i = 0; i < 4; ++i) {
            int idx = i * 256 + tid;
            int r = idx >> 3, cb = (idx & 7) * 8;
            async_copy16(Ab + (size_t)r * DIMSZ + k0 + cb,
                         (_Float16*)As + (size_t)(i * 256 + w * 64) * 8);
        }
        #pragma unroll
        for (int i = 0; i < 4; ++i) {
            int idx = i * 256 + tid;
            int r = idx >> 3, cb = (idx & 7) * 8;
            async_copy16(Bb + (size_t)r * DIMSZ + k0 + cb,
                         (_Float16*)Bs + (size_t)(i * 256 + w * 64) * 8);
        }
        __syncthreads();
        #pragma unroll
        for (int ks = 0; ks < 2; ++ks) {
            f16x8 af[4], bf[4];
            #pragma unroll
            for (int m = 0; m < 4; ++m)
                af[m] = *reinterpret_cast<const f16x8*>(&As[wr * 64 + m * 16 + lx][ks * 32 + g * 8]);
            #pragma unroll
            for (int n = 0; n < 4; ++n)
                bf[n] = *reinterpret_cast<const f16x8*>(&Bs[wc * 64 + n * 16 + lx][ks * 32 + g * 8]);
            #pragma unroll
            for (int m = 0; m < 4; ++m)
                #pragma unroll
                for (int n = 0; n < 4; ++n)
                    acc[m][n] = __builtin_amdgcn_mfma_f32_16x16x32_f16(af[m], bf[n], acc[m][n], 0, 0, 0);
        }
    }

    const int hcol0 = col0 + wc * 64;          // multiple of 64, one head
    const int proj  = hcol0 >> 10;
    const int hd    = (hcol0 & 1023) >> 6;
    float bsv[4];
    #pragma unroll
    for (int n = 0; n < 4; ++n) bsv[n] = bias[hcol0 + n * 16 + lx];

    if (proj == 2) {
        // ---- V: rope -> LDS transpose T[d][rlocal] -> coalesced (b,h,d,n) stores
        __syncthreads();
        _Float16* T = (_Float16*)smem;   // [128][136] = 34816B
        #pragma unroll
        for (int m = 0; m < 4; ++m) {
            int rl0 = wr * 64 + m * 16 + g * 4;
            #pragma unroll
            for (int r2 = 0; r2 < 4; ++r2) {
                int rlocal = rl0 + r2;
                int npos = (row0 + rlocal) & (SEQLEN - 1);
                const float* rcp = ropeC + npos * 32;
                const float* rsp = ropeS + npos * 32;
                #pragma unroll
                for (int n = 0; n < 4; ++n) {
                    float v = acc[m][n][r2] + bsv[n];
                    float o = __shfl_xor(v, 1);
                    int d = n * 16 + lx;
                    const float* tab = (d < 32) ? rcp : rsp;
                    float Rd = tab[d & 31];
                    float Rp = tab[(d & 31) ^ 1];
                    float y; int outc;
                    if (d & 1) { y = o * Rd + v * Rp; outc = (d >> 1) + 32; }
                    else       { y = v * Rd - o * Rp; outc = d >> 1; }
                    T[(wc * 64 + outc) * 136 + rlocal] = (_Float16)y;
                }
            }
        }
        __syncthreads();
        int b = row0 >> 11, npos0 = row0 & (SEQLEN - 1);
        int hd0 = (col0 & 1023) >> 6;
        #pragma unroll
        for (int i2 = 0; i2 < 8; ++i2) {
            int trow = w * 32 + i2 * 4 + g;
            int head = hd0 + (trow >> 6);
            int outd = trow & 63;
            f16x8 val = *reinterpret_cast<const f16x8*>(&T[trow * 136 + lx * 8]);
            *reinterpret_cast<f16x8*>(QKV + 8388608 +
                (((size_t)b * NHEADS + head) * HDIM + outd) * SEQLEN + npos0 + lx * 8) = val;
        }
    } else {
        #pragma unroll
        for (int m = 0; m < 4; ++m) {
            int rbase = row0 + wr * 64 + m * 16 + g * 4;
            #pragma unroll
            for (int r2 = 0; r2 < 4; ++r2) {
                int rglob = rbase + r2;
                int b = rglob >> 11, npos = rglob & (SEQLEN - 1);
                const float* rcp = ropeC + npos * 32;
                const float* rsp = ropeS + npos * 32;
                unsigned short* Orow = QKV +
                    ((((size_t)proj * BATCH + b) * NHEADS + hd) * SEQLEN + npos) * HDIM;
                #pragma unroll
                for (int n = 0; n < 4; ++n) {
                    float v = acc[m][n][r2] + bsv[n];   // x[d], d = n*16+lx
                    float o = __shfl_xor(v, 1);         // x[d^1]
                    int d = n * 16 + lx;
                    const float* tab = (d < 32) ? rcp : rsp;
                    float Rd = tab[d & 31];             // rope[d]
                    float Rp = tab[(d & 31) ^ 1];       // rope[d^1]
                    float y; int outc;
                    if (d & 1) { y = o * Rd + v * Rp; outc = (d >> 1) + 32; }
                    else       { y = v * Rd - o * Rp; outc = d >> 1; }
                    Orow[outc] = f16u(y);
                }
            }
        }
    }
}

// ---------------------------------------------------------------------------
// MFMA flash attention (f16), swapped QK^T + K=16 PV (P stays in registers,
// ZERO cross-lane redistribution) + double-buffered K/V^T staging (1 barrier
// per tile, prefetch hidden under compute).
// sacc[c] = S^T[key=c*16+g*4+r][q=lx]; after exp+cvt_pkrtz, pk[c] IS the
// 16x16x16 B-fragment (k=g*4+j). PV: O^T = mfma16(V^T-slice, pk[c]).
// LDS: buf0 {K 8KB | V^T 8KB} @0, buf1 @16384. XCD-aware flat grid.
// ---------------------------------------------------------------------------
__global__ __launch_bounds__(256) void attn_mfma_kernel(
    const unsigned short* __restrict__ QKV, const float* __restrict__ ropeC,
    const float* __restrict__ ropeS, unsigned short* __restrict__ Y)
{
    __shared__ __align__(16) unsigned char smem[32768];
    const int tid = threadIdx.x;
    const int w   = tid >> 6;
    const int l   = tid & 63;
    const int g   = l >> 4;
    const int lx  = l & 15;
    const int r8  = l >> 3;     // 0..7
    const int c8  = l & 7;      // chunk slot within row
    const int fb  = blockIdx.x;
    const int xcd = fb & 7, jj = fb >> 3;
    const int bh  = xcd * 4 + (jj & 3);       // 4 bh per XCD -> K/V L2-local
    const int b   = bh >> 4;
    const int h   = bh & 15;
    const int q0  = (jj >> 2) * 64;

    const unsigned short* Qb  = QKV + (size_t)bh * SEQLEN * HDIM;
    const unsigned short* Kb  = QKV + 4194304 + (size_t)bh * SEQLEN * HDIM;
    const unsigned short* Vtb = QKV + 8388608 + (size_t)bh * SEQLEN * HDIM;  // (d,n)

    f16x8 qf[2];
    {
        const unsigned short* src = Qb + (size_t)(q0 + w * 16 + lx) * HDIM + g * 8;
        qf[0] = *reinterpret_cast<const f16x8*>(src);
        qf[1] = *reinterpret_cast<const f16x8*>(src + 32);
    }
    f16x4 ones4;
    #pragma unroll
    for (int i = 0; i < 4; ++i) ones4[i] = (_Float16)1.0f;

    const float K2 = 0.18033688011112043f;    // 0.125 * log2(e)
    f32x4 oacc[4] = {};                        // O^T: d = c2*16+g*4+r, q = lx
    f32x4 lsum = {};
    float mrow = -1e30f;                       // per-lane: one q

    const int srow = w * 8 + r8;               // this thread's staging row base

    // ---- prologue: stage tile 0 into buf 0
    #pragma unroll
    for (int p = 0; p < 2; ++p) {
        int row = p * 32 + srow;
        int ch  = c8 ^ (row & 7);
        async_copy16(Kb  + (size_t)row * HDIM + ch * 8,
                     smem + p * 4096 + w * 1024);
        async_copy16(Vtb + (size_t)row * SEQLEN + ch * 8,
                     smem + 8192 + p * 4096 + w * 1024);
    }
    __syncthreads();

    int buf = 0;
    for (int kt = 0; kt < SEQLEN / 64; ++kt) {
        // ---- prefetch next tile into buf^1 (hidden under this tile's compute)
        if (kt + 1 < SEQLEN / 64) {
            const int k0n = (kt + 1) * 64;
            const int nb = (buf ^ 1) * 16384;
            #pragma unroll
            for (int p = 0; p < 2; ++p) {
                int row = p * 32 + srow;
                int ch  = c8 ^ (row & 7);
                async_copy16(Kb  + (size_t)(k0n + row) * HDIM + ch * 8,
                             smem + nb + p * 4096 + w * 1024);
                async_copy16(Vtb + (size_t)row * SEQLEN + k0n + ch * 8,
                             smem + nb + 8192 + p * 4096 + w * 1024);
            }
        }
        const int kb = buf * 16384;
        const int vb = kb + 8192;

        // ---- swapped QK^T: sacc[c] = S^T[key = c*16+g*4+r][q = lx]
        f32x4 sacc[4] = {};
        #pragma unroll
        for (int c = 0; c < 4; ++c) {
            int key = c * 16 + lx;
            int rowb = kb + key * 128, sw = (key & 7) << 4;
            f16x8 k0f = *reinterpret_cast<const f16x8*>(&smem[rowb + ((g * 16) ^ sw)]);
            f16x8 k1f = *reinterpret_cast<const f16x8*>(&smem[rowb + ((64 + g * 16) ^ sw)]);
            sacc[c] = __builtin_amdgcn_mfma_f32_16x16x32_f16(k0f, qf[0], sacc[c], 0, 0, 0);
            sacc[c] = __builtin_amdgcn_mfma_f32_16x16x32_f16(k1f, qf[1], sacc[c], 0, 0, 0);
        }

        // ---- softmax, deferred max (THR = 64 raw = 8 post-scale)
        float lmax = sacc[0][0];
        #pragma unroll
        for (int c = 0; c < 4; ++c)
            #pragma unroll
            for (int r = 0; r < 4; ++r) lmax = fmaxf(lmax, sacc[c][r]);
        bool ok = (lmax <= mrow + 64.f);
        if (!__all((int)ok)) {
            float m2 = fmaxf(lmax, __shfl_xor(lmax, 16));
            m2 = fmaxf(m2, __shfl_xor(m2, 32));
            float mnew = fmaxf(mrow, m2);
            float sc = exp2f((mrow - mnew) * K2);
            mrow = mnew;
            #pragma unroll
            for (int r = 0; r < 4; ++r) lsum[r] *= sc;
            #pragma unroll
            for (int c = 0; c < 4; ++c)
                #pragma unroll
                for (int r = 0; r < 4; ++r) oacc[c][r] *= sc;
        }
        float mk = -mrow * K2;
        #pragma unroll
        for (int c = 0; c < 4; ++c)
            #pragma unroll
            for (int r = 0; r < 4; ++r)
                sacc[c][r] = exp2f(fmaf(sacc[c][r], K2, mk));

        // ---- pack P: pk[c] = B-frag of 16x16x16 (k = g*4+j), q = lx. NO shfl.
        #pragma unroll
        for (int c = 0; c < 4; ++c) {
            unsigned p0 = __builtin_bit_cast(unsigned,
                __builtin_amdgcn_cvt_pkrtz(sacc[c][0], sacc[c][1]));
            unsigned p1 = __builtin_bit_cast(unsigned,
                __builtin_amdgcn_cvt_pkrtz(sacc[c][2], sacc[c][3]));
            u32x2 pw = { p0, p1 };
            f16x4 pfrag = __builtin_bit_cast(f16x4, pw);
            lsum = __builtin_amdgcn_mfma_f32_16x16x16f16(ones4, pfrag, lsum, 0, 0, 0);
            #pragma unroll
            for (int c2 = 0; c2 < 4; ++c2) {
                int d = c2 * 16 + lx;
                f16x4 vf4 = *reinterpret_cast<const f16x4*>(
                    &smem[vb + d * 128 + ((c * 32 + g * 8) ^ ((d & 7) << 4))]);
                oacc[c2] = __builtin_amdgcn_mfma_f32_16x16x16f16(vf4, pfrag, oacc[c2], 0, 0, 0);
            }
        }

        __syncthreads();   // next buf staged + all waves done reading cur buf
        buf ^= 1;
    }

    // ---- epilogue: normalize, -rope (lane-local pairs), packed dword stores
    float inv = 1.0f / lsum[0];
    const int q = q0 + w * 16 + lx;
    unsigned short* drow = Y + ((size_t)b * SEQLEN + q) * DIMSZ + h * HDIM;
    #pragma unroll
    for (int c = 0; c < 4; ++c) {
        const float* tab = ((c < 2) ? ropeC : ropeS) + (size_t)q * 32;
        unsigned short lo16[2], hi16[2];
        #pragma unroll
        for (int rp = 0; rp < 2; ++rp) {
            int d = c * 16 + g * 4 + 2 * rp;        // even d
            float v0 = oacc[c][2 * rp] * inv;
            float v1 = oacc[c][2 * rp + 1] * inv;
            float Rd = tab[d & 31], Rn = tab[(d & 31) + 1];
            lo16[rp] = f16u(-(v0 * Rd - v1 * Rn));
            hi16[rp] = f16u(-(v0 * Rn + v1 * Rd));
        }
        int p = c * 8 + g * 2;                       // even column
        *reinterpret_cast<unsigned*>(&drow[p])      = (unsigned)lo16[0] | ((unsigned)lo16[1] << 16);
        *reinterpret_cast<unsigned*>(&drow[p + 32]) = (unsigned)hi16[0] | ((unsigned)hi16[1] << 16);
    }
}

// ---------------------------------------------------------------------------
// Out GEMM: out[4096 x 1024] = Y16 @ Wo16^T + bo (f32 out)
// ---------------------------------------------------------------------------
__global__ __launch_bounds__(256) void out_gemm_kernel(
    const unsigned short* __restrict__ A, const unsigned short* __restrict__ B,
    const float* __restrict__ bias, float* __restrict__ Out)
{
    __shared__ __align__(16) _Float16 As[128][64];
    __shared__ __align__(16) _Float16 Bs[128][64];
    const int tid = threadIdx.x;
    const int w = tid >> 6, lane = tid & 63;
    const int g = lane >> 4, lx = lane & 15;
    const int wr = w >> 1, wc = w & 1;
    const int row0 = blockIdx.y * 128;
    const int col0 = blockIdx.x * 128;
    const unsigned short* Ab = A + (size_t)row0 * DIMSZ;
    const unsigned short* Bb = B + (size_t)col0 * DIMSZ;

    f32x4 acc[4][4] = {};
    for (int k0 = 0; k0 < DIMSZ; k0 += 64) {
        __syncthreads();
        #pragma unroll
        for (int i = 0; i < 4; ++i) {
            int idx = i * 256 + tid;
            int r = idx >> 3, cb = (idx & 7) * 8;
            async_copy16(Ab + (size_t)r * DIMSZ + k0 + cb,
                         (_Float16*)As + (size_t)(i * 256 + w * 64) * 8);
        }
        #pragma unroll
        for (int i = 0; i < 4; ++i) {
            int idx = i * 256 + tid;
            int r = idx >> 3, cb = (idx & 7) * 8;
            async_copy16(Bb + (size_t)r * DIMSZ + k0 + cb,
                         (_Float16*)Bs + (size_t)(i * 256 + w * 64) * 8);
        }
        __syncthreads();
        #pragma unroll
        for (int ks = 0; ks < 2; ++ks) {
            f16x8 af[4], bf[4];
            #pragma unroll
            for (int m = 0; m < 4; ++m)
                af[m] = *reinterpret_cast<const f16x8*>(&As[wr * 64 + m * 16 + lx][ks * 32 + g * 8]);
            #pragma unroll
            for (int n = 0; n < 4; ++n)
                bf[n] = *reinterpret_cast<const f16x8*>(&Bs[wc * 64 + n * 16 + lx][ks * 32 + g * 8]);
            #pragma unroll
            for (int m = 0; m < 4; ++m)
                #pragma unroll
                for (int n = 0; n < 4; ++n)
                    acc[m][n] = __builtin_amdgcn_mfma_f32_16x16x32_f16(af[m], bf[n], acc[m][n], 0, 0, 0);
        }
    }

    const int cb0 = col0 + wc * 64;
    float bsv[4];
    #pragma unroll
    for (int n = 0; n < 4; ++n) bsv[n] = bias[cb0 + n * 16 + lx];
    #pragma unroll
    for (int m = 0; m < 4; ++m) {
        int rbase = row0 + wr * 64 + m * 16 + g * 4;
        #pragma unroll
        for (int r2 = 0; r2 < 4; ++r2) {
            float* orow = Out + (size_t)(rbase + r2) * DIMSZ + cb0;
            #pragma unroll
            for (int n = 0; n < 4; ++n)
                orow[n * 16 + lx] = acc[m][n][r2] + bsv[n];
        }
    }
}

extern "C" void kernel_launch(void* const* d_in, const int* in_sizes, int n_in,
                              void* d_out, int out_size, void* d_ws, size_t ws_size,
                              hipStream_t stream) {
    const float* x  = (const float*)d_in[0];
    const float* Wq = (const float*)d_in[1];
    const float* bq = (const float*)d_in[2];
    const float* Wk = (const float*)d_in[3];
    const float* bk = (const float*)d_in[4];
    const float* Wv = (const float*)d_in[5];
    const float* bv = (const float*)d_in[6];
    const float* Wo = (const float*)d_in[7];
    const float* bo = (const float*)d_in[8];
    float* out = (float*)d_out;

    char* ws = (char*)d_ws;
    unsigned short* x16    = (unsigned short*)(ws);
    unsigned short* Wqkv16 = (unsigned short*)(ws + 8388608);
    unsigned short* Wo16   = (unsigned short*)(ws + 14680064);
    float* biasqkv         = (float*)(ws + 16777216);
    float* ropeC           = (float*)(ws + 16793600);
    float* ropeS           = (float*)(ws + 17055744);
    unsigned short* QKVw   = (unsigned short*)(ws + 17825792);
    unsigned short* Yw     = (unsigned short*)(ws + 42991616);

    dim3 blk(256);
    prep_kernel<<<dim3(2048), blk, 0, stream>>>(x, Wq, Wk, Wv, Wo, bq, bk, bv,
                                                x16, Wqkv16, Wo16, biasqkv, ropeC, ropeS);
    qkv_gemm_kernel<<<dim3(24, 32), blk, 0, stream>>>(x16, Wqkv16, biasqkv, ropeC, ropeS, QKVw);
    attn_mfma_kernel<<<dim3(1024), blk, 0, stream>>>(QKVw, ropeC, ropeS, Yw);
    out_gemm_kernel<<<dim3(8, 32), blk, 0, stream>>>(Yw, Wo16, bo, out);
}

// Round 12
// 176.877 us; speedup vs baseline: 1.0585x; 1.0336x over previous
//
#include <hip/hip_runtime.h>
#include <hip/hip_bf16.h>
#include <math.h>

#define NHEADS 16
#define HDIM   64
#define BATCH  2
#define SEQLEN 2048
#define DIMSZ  1024

typedef _Float16 f16x8 __attribute__((ext_vector_type(8)));
typedef _Float16 f16x4 __attribute__((ext_vector_type(4)));
typedef float    f32x4 __attribute__((ext_vector_type(4)));
typedef unsigned short u16x8 __attribute__((ext_vector_type(8)));
typedef unsigned int   u32x2 __attribute__((ext_vector_type(2)));

__device__ __forceinline__ float rope_theta(int c) {
    int i = c & 31;
    return (float)pow(10000.0, -(double)i / 32.0);
}
__device__ __forceinline__ unsigned short f16u(float f) {
    _Float16 h = (_Float16)f;
    return *reinterpret_cast<unsigned short*>(&h);
}
__device__ __forceinline__ void async_copy16(const void* gsrc, void* lds) {
    __builtin_amdgcn_global_load_lds(
        (const __attribute__((address_space(1))) unsigned int*)gsrc,
        (__attribute__((address_space(3))) unsigned int*)lds, 16, 0, 0);
}

// ---------------------------------------------------------------------------
// prep: f32->f16 conversions (x, Wq|Wk|Wv concat, Wo), bias concat, rope tables
// ---------------------------------------------------------------------------
__global__ __launch_bounds__(256) void prep_kernel(
    const float* __restrict__ x, const float* __restrict__ Wq,
    const float* __restrict__ Wk, const float* __restrict__ Wv,
    const float* __restrict__ Wo, const float* __restrict__ bq,
    const float* __restrict__ bk, const float* __restrict__ bv,
    unsigned short* __restrict__ x16, unsigned short* __restrict__ Wqkv16,
    unsigned short* __restrict__ Wo16, float* __restrict__ biasqkv,
    float* __restrict__ ropeC, float* __restrict__ ropeS)
{
    const int NV = (4194304 + 4 * 1048576) / 8;   // 1,048,576 vec8 chunks
    int gid = blockIdx.x * 256 + threadIdx.x;
    for (int i = gid; i < NV; i += gridDim.x * 256) {
        long e = (long)i * 8;
        const float* src; unsigned short* dst; long off;
        if (e < 4194304)      { src = x;  dst = x16;              off = e; }
        else if (e < 5242880) { src = Wq; dst = Wqkv16;           off = e - 4194304; }
        else if (e < 6291456) { src = Wk; dst = Wqkv16 + 1048576; off = e - 5242880; }
        else if (e < 7340032) { src = Wv; dst = Wqkv16 + 2097152; off = e - 6291456; }
        else                  { src = Wo; dst = Wo16;             off = e - 7340032; }
        float4 v0 = *reinterpret_cast<const float4*>(src + off);
        float4 v1 = *reinterpret_cast<const float4*>(src + off + 4);
        u16x8 o;
        o[0] = f16u(v0.x); o[1] = f16u(v0.y); o[2] = f16u(v0.z); o[3] = f16u(v0.w);
        o[4] = f16u(v1.x); o[5] = f16u(v1.y); o[6] = f16u(v1.z); o[7] = f16u(v1.w);
        *reinterpret_cast<u16x8*>(dst + off) = o;
    }
    if (gid < 65536) {
        int npos = gid >> 5, j = gid & 31;
        float f = (float)npos * rope_theta(j);
        ropeC[gid] = cosf(f);
        ropeS[gid] = sinf(f);
    }
    if (gid < 3072) {
        biasqkv[gid] = gid < 1024 ? bq[gid] : (gid < 2048 ? bk[gid - 1024] : bv[gid - 2048]);
    }
}

// ---------------------------------------------------------------------------
// Fused QKV GEMM + bias + (non-standard) rope.
//   Q, K -> (b,h,n,d) f16;  V -> TRANSPOSED (b,h,d,n) f16 via LDS transpose.
//   out[p]    = x[2p]*rope[2p]   - x[2p+1]*rope[2p+1]
//   out[p+32] = x[2p]*rope[2p+1] + x[2p+1]*rope[2p]
// ---------------------------------------------------------------------------
__global__ __launch_bounds__(256) void qkv_gemm_kernel(
    const unsigned short* __restrict__ A, const unsigned short* __restrict__ B,
    const float* __restrict__ bias, const float* __restrict__ ropeC,
    const float* __restrict__ ropeS, unsigned short* __restrict__ QKV)
{
    __shared__ __align__(16) unsigned char smem[34816];   // max(As+Bs 32768, T 34816)
    _Float16 (*As)[64] = (_Float16(*)[64])smem;            // [128][64]
    _Float16 (*Bs)[64] = (_Float16(*)[64])(smem + 16384);  // [128][64]
    const int tid = threadIdx.x;
    const int w = tid >> 6, lane = tid & 63;
    const int g = lane >> 4, lx = lane & 15;
    const int wr = w >> 1, wc = w & 1;
    const int row0 = blockIdx.y * 128;
    const int col0 = blockIdx.x * 128;
    const unsigned short* Ab = A + (size_t)row0 * DIMSZ;
    const unsigned short* Bb = B + (size_t)col0 * DIMSZ;

    f32x4 acc[4][4] = {};
    for (int k0 = 0; k0 < DIMSZ; k0 += 64) {
        __syncthreads();
        #pragma unroll
        for (int i = 0; i < 4; ++i) {
            int idx = i * 256 + tid;
            int r = idx >> 3, cb = (idx & 7) * 8;
            async_copy16(Ab + (size_t)r * DIMSZ + k0 + cb,
                         (_Float16*)As + (size_t)(i * 256 + w * 64) * 8);
        }
        #pragma unroll
        for (int i = 0; i < 4; ++i) {
            int idx = i * 256 + tid;
            int r = idx >> 3, cb = (idx & 7) * 8;
            async_copy16(Bb + (size_t)r * DIMSZ + k0 + cb,
                         (_Float16*)Bs + (size_t)(i * 256 + w * 64) * 8);
        }
        __syncthreads();
        #pragma unroll
        for (int ks = 0; ks < 2; ++ks) {
            f16x8 af[4], bf[4];
            #pragma unroll
            for (int m = 0; m < 4; ++m)
                af[m] = *reinterpret_cast<const f16x8*>(&As[wr * 64 + m * 16 + lx][ks * 32 + g * 8]);
            #pragma unroll
            for (int n = 0; n < 4; ++n)
                bf[n] = *reinterpret_cast<const f16x8*>(&Bs[wc * 64 + n * 16 + lx][ks * 32 + g * 8]);
            #pragma unroll
            for (int m = 0; m < 4; ++m)
                #pragma unroll
                for (int n = 0; n < 4; ++n)
                    acc[m][n] = __builtin_amdgcn_mfma_f32_16x16x32_f16(af[m], bf[n], acc[m][n], 0, 0, 0);
        }
    }

    const int hcol0 = col0 + wc * 64;          // multiple of 64, one head
    const int proj  = hcol0 >> 10;
    const int hd    = (hcol0 & 1023) >> 6;
    float bsv[4];
    #pragma unroll
    for (int n = 0; n < 4; ++n) bsv[n] = bias[hcol0 + n * 16 + lx];

    if (proj == 2) {
        // ---- V: rope -> LDS transpose T[d][rlocal] -> coalesced (b,h,d,n) stores
        __syncthreads();
        _Float16* T = (_Float16*)smem;   // [128][136] = 34816B
        #pragma unroll
        for (int m = 0; m < 4; ++m) {
            int rl0 = wr * 64 + m * 16 + g * 4;
            #pragma unroll
            for (int r2 = 0; r2 < 4; ++r2) {
                int rlocal = rl0 + r2;
                int npos = (row0 + rlocal) & (SEQLEN - 1);
                const float* rcp = ropeC + npos * 32;
                const float* rsp = ropeS + npos * 32;
                #pragma unroll
                for (int n = 0; n < 4; ++n) {
                    float v = acc[m][n][r2] + bsv[n];
                    float o = __shfl_xor(v, 1);
                    int d = n * 16 + lx;
                    const float* tab = (d < 32) ? rcp : rsp;
                    float Rd = tab[d & 31];
                    float Rp = tab[(d & 31) ^ 1];
                    float y; int outc;
                    if (d & 1) { y = o * Rd + v * Rp; outc = (d >> 1) + 32; }
                    else       { y = v * Rd - o * Rp; outc = d >> 1; }
                    T[(wc * 64 + outc) * 136 + rlocal] = (_Float16)y;
                }
            }
        }
        __syncthreads();
        int b = row0 >> 11, npos0 = row0 & (SEQLEN - 1);
        int hd0 = (col0 & 1023) >> 6;
        #pragma unroll
        for (int i2 = 0; i2 < 8; ++i2) {
            int trow = w * 32 + i2 * 4 + g;
            int head = hd0 + (trow >> 6);
            int outd = trow & 63;
            f16x8 val = *reinterpret_cast<const f16x8*>(&T[trow * 136 + lx * 8]);
            *reinterpret_cast<f16x8*>(QKV + 8388608 +
                (((size_t)b * NHEADS + head) * HDIM + outd) * SEQLEN + npos0 + lx * 8) = val;
        }
    } else {
        #pragma unroll
        for (int m = 0; m < 4; ++m) {
            int rbase = row0 + wr * 64 + m * 16 + g * 4;
            #pragma unroll
            for (int r2 = 0; r2 < 4; ++r2) {
                int rglob = rbase + r2;
                int b = rglob >> 11, npos = rglob & (SEQLEN - 1);
                const float* rcp = ropeC + npos * 32;
                const float* rsp = ropeS + npos * 32;
                unsigned short* Orow = QKV +
                    ((((size_t)proj * BATCH + b) * NHEADS + hd) * SEQLEN + npos) * HDIM;
                #pragma unroll
                for (int n = 0; n < 4; ++n) {
                    float v = acc[m][n][r2] + bsv[n];   // x[d], d = n*16+lx
                    float o = __shfl_xor(v, 1);         // x[d^1]
                    int d = n * 16 + lx;
                    const float* tab = (d < 32) ? rcp : rsp;
                    float Rd = tab[d & 31];             // rope[d]
                    float Rp = tab[(d & 31) ^ 1];       // rope[d^1]
                    float y; int outc;
                    if (d & 1) { y = o * Rd + v * Rp; outc = (d >> 1) + 32; }
                    else       { y = v * Rd - o * Rp; outc = d >> 1; }
                    Orow[outc] = f16u(y);
                }
            }
        }
    }
}

// ---------------------------------------------------------------------------
// MFMA flash attention (f16), 8 waves = 4 q-groups x 2 KEY-HALVES.
// Each wave: independent online softmax over its 32-key stream (swapped
// QK^T, reg-resident P, K=16 PV). Key-half partials (m,l,O) merged once at
// the end via LDS (flash-merge). Double-buffered staging, 1 barrier/tile.
// LDS: buf{0,1} = {K 8KB | V^T 8KB}; merge area reuses buf space at end.
// ---------------------------------------------------------------------------
__global__ __launch_bounds__(512, 8) void attn_mfma_kernel(
    const unsigned short* __restrict__ QKV, const float* __restrict__ ropeC,
    const float* __restrict__ ropeS, unsigned short* __restrict__ Y)
{
    __shared__ __align__(16) unsigned char smem[32768];
    const int tid = threadIdx.x;
    const int w   = tid >> 6;
    const int l   = tid & 63;
    const int g   = l >> 4;
    const int lx  = l & 15;
    const int qg  = w & 3;      // q-group: 16 q per wave
    const int kh  = w >> 2;     // key half: 0 -> keys 0..31, 1 -> keys 32..63
    const int fb  = blockIdx.x;
    const int xcd = fb & 7, jj = fb >> 3;
    const int bh  = xcd * 4 + (jj & 3);       // 4 bh per XCD -> K/V L2-local
    const int b   = bh >> 4;
    const int h   = bh & 15;
    const int q0  = (jj >> 2) * 64;

    const unsigned short* Qb  = QKV + (size_t)bh * SEQLEN * HDIM;
    const unsigned short* Kb  = QKV + 4194304 + (size_t)bh * SEQLEN * HDIM;
    const unsigned short* Vtb = QKV + 8388608 + (size_t)bh * SEQLEN * HDIM;  // (d,n)

    f16x8 qf[2];
    {
        const unsigned short* src = Qb + (size_t)(q0 + qg * 16 + lx) * HDIM + g * 8;
        qf[0] = *reinterpret_cast<const f16x8*>(src);
        qf[1] = *reinterpret_cast<const f16x8*>(src + 32);
    }
    f16x4 ones4;
    #pragma unroll
    for (int i = 0; i < 4; ++i) ones4[i] = (_Float16)1.0f;

    const float K2 = 0.18033688011112043f;    // 0.125 * log2(e)
    f32x4 oacc[4] = {};                        // O^T partial: d=c2*16+g*4+r, q=lx
    f32x4 lsum = {};
    float mrow = -1e30f;                       // per-lane: one q, this key-half

    // staging: 512 threads cover 64 rows x 8 chunks per array
    const int srow = tid >> 3;                 // 0..63
    const int c8   = tid & 7;
    const int sch  = c8 ^ (srow & 7);          // inverse-swizzled source chunk
    const int sdst = tid * 16;                 // linear LDS dest (wave-uniform+lane*16)

    // ---- prologue: stage tile 0 into buf 0
    async_copy16(Kb  + (size_t)srow * HDIM + sch * 8, smem + sdst);
    async_copy16(Vtb + (size_t)srow * SEQLEN + sch * 8, smem + 8192 + sdst);
    __syncthreads();

    int buf = 0;
    for (int kt = 0; kt < SEQLEN / 64; ++kt) {
        // ---- prefetch next tile into buf^1 (hidden under this tile's compute)
        if (kt + 1 < SEQLEN / 64) {
            const int k0n = (kt + 1) * 64;
            const int nb = (buf ^ 1) * 16384;
            async_copy16(Kb  + (size_t)(k0n + srow) * HDIM + sch * 8,
                         smem + nb + sdst);
            async_copy16(Vtb + (size_t)srow * SEQLEN + k0n + sch * 8,
                         smem + nb + 8192 + sdst);
        }
        const int kb = buf * 16384;
        const int vb = kb + 8192;

        // ---- swapped QK^T over this wave's 32 keys:
        //      sacc[c] = S^T[key = kh*32 + c*16 + g*4 + r][q = lx]
        f32x4 sacc[2] = {};
        __builtin_amdgcn_s_setprio(1);
        #pragma unroll
        for (int c = 0; c < 2; ++c) {
            int key = kh * 32 + c * 16 + lx;
            int rowb = kb + key * 128, sw = (key & 7) << 4;
            f16x8 k0f = *reinterpret_cast<const f16x8*>(&smem[rowb + ((g * 16) ^ sw)]);
            f16x8 k1f = *reinterpret_cast<const f16x8*>(&smem[rowb + ((64 + g * 16) ^ sw)]);
            sacc[c] = __builtin_amdgcn_mfma_f32_16x16x32_f16(k0f, qf[0], sacc[c], 0, 0, 0);
            sacc[c] = __builtin_amdgcn_mfma_f32_16x16x32_f16(k1f, qf[1], sacc[c], 0, 0, 0);
        }
        __builtin_amdgcn_s_setprio(0);

        // ---- softmax, deferred max (THR = 64 raw = 8 post-scale)
        float lmax = sacc[0][0];
        #pragma unroll
        for (int c = 0; c < 2; ++c)
            #pragma unroll
            for (int r = 0; r < 4; ++r) lmax = fmaxf(lmax, sacc[c][r]);
        bool ok = (lmax <= mrow + 64.f);
        if (!__all((int)ok)) {
            float m2 = fmaxf(lmax, __shfl_xor(lmax, 16));
            m2 = fmaxf(m2, __shfl_xor(m2, 32));
            float mnew = fmaxf(mrow, m2);
            float sc = exp2f((mrow - mnew) * K2);
            mrow = mnew;
            #pragma unroll
            for (int r = 0; r < 4; ++r) lsum[r] *= sc;
            #pragma unroll
            for (int c = 0; c < 4; ++c)
                #pragma unroll
                for (int r = 0; r < 4; ++r) oacc[c][r] *= sc;
        }
        float mk = -mrow * K2;
        #pragma unroll
        for (int c = 0; c < 2; ++c)
            #pragma unroll
            for (int r = 0; r < 4; ++r)
                sacc[c][r] = exp2f(fmaf(sacc[c][r], K2, mk));

        // ---- pack P (B-frag of 16x16x16, k=g*4+j) + PV, zero cross-lane
        #pragma unroll
        for (int c = 0; c < 2; ++c) {
            unsigned p0 = __builtin_bit_cast(unsigned,
                __builtin_amdgcn_cvt_pkrtz(sacc[c][0], sacc[c][1]));
            unsigned p1 = __builtin_bit_cast(unsigned,
                __builtin_amdgcn_cvt_pkrtz(sacc[c][2], sacc[c][3]));
            u32x2 pw = { p0, p1 };
            f16x4 pfrag = __builtin_bit_cast(f16x4, pw);
            __builtin_amdgcn_s_setprio(1);
            lsum = __builtin_amdgcn_mfma_f32_16x16x16f16(ones4, pfrag, lsum, 0, 0, 0);
            #pragma unroll
            for (int c2 = 0; c2 < 4; ++c2) {
                int d = c2 * 16 + lx;
                int off = kh * 64 + c * 32 + g * 8;
                f16x4 vf4 = *reinterpret_cast<const f16x4*>(
                    &smem[vb + d * 128 + (off ^ ((d & 7) << 4))]);
                oacc[c2] = __builtin_amdgcn_mfma_f32_16x16x16f16(vf4, pfrag, oacc[c2], 0, 0, 0);
            }
            __builtin_amdgcn_s_setprio(0);
        }

        __syncthreads();   // next buf staged + all waves done reading cur buf
        buf ^= 1;
    }

    // ---- key-half merge via LDS (flash-merge), then -rope epilogue
    // area per qg: O[16q][68] f32 (4352B) + M[16] + L[16] -> 1120 floats
    float* Of = (float*)smem + qg * 1120;
    if (kh == 1) {
        #pragma unroll
        for (int c2 = 0; c2 < 4; ++c2)
            *reinterpret_cast<f32x4*>(&Of[lx * 68 + c2 * 16 + g * 4]) = oacc[c2];
        if (g == 0) {
            Of[1088 + lx] = mrow;
            Of[1104 + lx] = lsum[0];
        }
    }
    __syncthreads();
    if (kh == 0) {
        float m_hi = Of[1088 + lx];
        float l_hi = Of[1104 + lx];
        float M = fmaxf(mrow, m_hi);
        float a  = exp2f((mrow - M) * K2);
        float bb = exp2f((m_hi - M) * K2);
        float inv = 1.0f / (a * lsum[0] + bb * l_hi);
        const int q = q0 + qg * 16 + lx;
        unsigned short* drow = Y + ((size_t)b * SEQLEN + q) * DIMSZ + h * HDIM;
        #pragma unroll
        for (int c2 = 0; c2 < 4; ++c2) {
            f32x4 ohi = *reinterpret_cast<const f32x4*>(&Of[lx * 68 + c2 * 16 + g * 4]);
            const float* tab = ((c2 < 2) ? ropeC : ropeS) + (size_t)q * 32;
            unsigned short lo16[2], hi16[2];
            #pragma unroll
            for (int rp = 0; rp < 2; ++rp) {
                int d = c2 * 16 + g * 4 + 2 * rp;        // even d
                float v0 = (a * oacc[c2][2 * rp]     + bb * ohi[2 * rp])     * inv;
                float v1 = (a * oacc[c2][2 * rp + 1] + bb * ohi[2 * rp + 1]) * inv;
                float Rd = tab[d & 31], Rn = tab[(d & 31) + 1];
                lo16[rp] = f16u(-(v0 * Rd - v1 * Rn));
                hi16[rp] = f16u(-(v0 * Rn + v1 * Rd));
            }
            int p = c2 * 8 + g * 2;                       // even column
            *reinterpret_cast<unsigned*>(&drow[p])      = (unsigned)lo16[0] | ((unsigned)lo16[1] << 16);
            *reinterpret_cast<unsigned*>(&drow[p + 32]) = (unsigned)hi16[0] | ((unsigned)hi16[1] << 16);
        }
    }
}

// ---------------------------------------------------------------------------
// Out GEMM: out[4096 x 1024] = Y16 @ Wo16^T + bo (f32 out)
// ---------------------------------------------------------------------------
__global__ __launch_bounds__(256) void out_gemm_kernel(
    const unsigned short* __restrict__ A, const unsigned short* __restrict__ B,
    const float* __restrict__ bias, float* __restrict__ Out)
{
    __shared__ __align__(16) _Float16 As[128][64];
    __shared__ __align__(16) _Float16 Bs[128][64];
    const int tid = threadIdx.x;
    const int w = tid >> 6, lane = tid & 63;
    const int g = lane >> 4, lx = lane & 15;
    const int wr = w >> 1, wc = w & 1;
    const int row0 = blockIdx.y * 128;
    const int col0 = blockIdx.x * 128;
    const unsigned short* Ab = A + (size_t)row0 * DIMSZ;
    const unsigned short* Bb = B + (size_t)col0 * DIMSZ;

    f32x4 acc[4][4] = {};
    for (int k0 = 0; k0 < DIMSZ; k0 += 64) {
        __syncthreads();
        #pragma unroll
        for (int i = 0; i < 4; ++i) {
            int idx = i * 256 + tid;
            int r = idx >> 3, cb = (idx & 7) * 8;
            async_copy16(Ab + (size_t)r * DIMSZ + k0 + cb,
                         (_Float16*)As + (size_t)(i * 256 + w * 64) * 8);
        }
        #pragma unroll
        for (int i = 0; i < 4; ++i) {
            int idx = i * 256 + tid;
            int r = idx >> 3, cb = (idx & 7) * 8;
            async_copy16(Bb + (size_t)r * DIMSZ + k0 + cb,
                         (_Float16*)Bs + (size_t)(i * 256 + w * 64) * 8);
        }
        __syncthreads();
        #pragma unroll
        for (int ks = 0; ks < 2; ++ks) {
            f16x8 af[4], bf[4];
            #pragma unroll
            for (int m = 0; m < 4; ++m)
                af[m] = *reinterpret_cast<const f16x8*>(&As[wr * 64 + m * 16 + lx][ks * 32 + g * 8]);
            #pragma unroll
            for (int n = 0; n < 4; ++n)
                bf[n] = *reinterpret_cast<const f16x8*>(&Bs[wc * 64 + n * 16 + lx][ks * 32 + g * 8]);
            #pragma unroll
            for (int m = 0; m < 4; ++m)
                #pragma unroll
                for (int n = 0; n < 4; ++n)
                    acc[m][n] = __builtin_amdgcn_mfma_f32_16x16x32_f16(af[m], bf[n], acc[m][n], 0, 0, 0);
        }
    }

    const int cb0 = col0 + wc * 64;
    float bsv[4];
    #pragma unroll
    for (int n = 0; n < 4; ++n) bsv[n] = bias[cb0 + n * 16 + lx];
    #pragma unroll
    for (int m = 0; m < 4; ++m) {
        int rbase = row0 + wr * 64 + m * 16 + g * 4;
        #pragma unroll
        for (int r2 = 0; r2 < 4; ++r2) {
            float* orow = Out + (size_t)(rbase + r2) * DIMSZ + cb0;
            #pragma unroll
            for (int n = 0; n < 4; ++n)
                orow[n * 16 + lx] = acc[m][n][r2] + bsv[n];
        }
    }
}

extern "C" void kernel_launch(void* const* d_in, const int* in_sizes, int n_in,
                              void* d_out, int out_size, void* d_ws, size_t ws_size,
                              hipStream_t stream) {
    const float* x  = (const float*)d_in[0];
    const float* Wq = (const float*)d_in[1];
    const float* bq = (const float*)d_in[2];
    const float* Wk = (const float*)d_in[3];
    const float* bk = (const float*)d_in[4];
    const float* Wv = (const float*)d_in[5];
    const float* bv = (const float*)d_in[6];
    const float* Wo = (const float*)d_in[7];
    const float* bo = (const float*)d_in[8];
    float* out = (float*)d_out;

    char* ws = (char*)d_ws;
    unsigned short* x16    = (unsigned short*)(ws);
    unsigned short* Wqkv16 = (unsigned short*)(ws + 8388608);
    unsigned short* Wo16   = (unsigned short*)(ws + 14680064);
    float* biasqkv         = (float*)(ws + 16777216);
    float* ropeC           = (float*)(ws + 16793600);
    float* ropeS           = (float*)(ws + 17055744);
    unsigned short* QKVw   = (unsigned short*)(ws + 17825792);
    unsigned short* Yw     = (unsigned short*)(ws + 42991616);

    dim3 blk(256);
    prep_kernel<<<dim3(2048), blk, 0, stream>>>(x, Wq, Wk, Wv, Wo, bq, bk, bv,
                                                x16, Wqkv16, Wo16, biasqkv, ropeC, ropeS);
    qkv_gemm_kernel<<<dim3(24, 32), blk, 0, stream>>>(x16, Wqkv16, biasqkv, ropeC, ropeS, QKVw);
    attn_mfma_kernel<<<dim3(1024), dim3(512), 0, stream>>>(QKVw, ropeC, ropeS, Yw);
    out_gemm_kernel<<<dim3(8, 32), blk, 0, stream>>>(Yw, Wo16, bo, out);
}

// Round 13
// 140.579 us; speedup vs baseline: 1.3318x; 1.2582x over previous
//
#include <hip/hip_runtime.h>
#include <hip/hip_bf16.h>
#include <math.h>

#define NHEADS 16
#define HDIM   64
#define BATCH  2
#define SEQLEN 2048
#define DIMSZ  1024

typedef _Float16 f16x8 __attribute__((ext_vector_type(8)));
typedef _Float16 f16x4 __attribute__((ext_vector_type(4)));
typedef float    f32x4 __attribute__((ext_vector_type(4)));
typedef unsigned short u16x8 __attribute__((ext_vector_type(8)));
typedef unsigned int   u32x2 __attribute__((ext_vector_type(2)));

__device__ __forceinline__ float rope_theta(int c) {
    int i = c & 31;
    return (float)pow(10000.0, -(double)i / 32.0);
}
__device__ __forceinline__ unsigned short f16u(float f) {
    _Float16 h = (_Float16)f;
    return *reinterpret_cast<unsigned short*>(&h);
}
__device__ __forceinline__ void async_copy16(const void* gsrc, void* lds) {
    __builtin_amdgcn_global_load_lds(
        (const __attribute__((address_space(1))) unsigned int*)gsrc,
        (__attribute__((address_space(3))) unsigned int*)lds, 16, 0, 0);
}

// ---------------------------------------------------------------------------
// prep: f32->f16 conversions (x, Wq|Wk|Wv concat, Wo), bias concat, rope tables
// ---------------------------------------------------------------------------
__global__ __launch_bounds__(256) void prep_kernel(
    const float* __restrict__ x, const float* __restrict__ Wq,
    const float* __restrict__ Wk, const float* __restrict__ Wv,
    const float* __restrict__ Wo, const float* __restrict__ bq,
    const float* __restrict__ bk, const float* __restrict__ bv,
    unsigned short* __restrict__ x16, unsigned short* __restrict__ Wqkv16,
    unsigned short* __restrict__ Wo16, float* __restrict__ biasqkv,
    float* __restrict__ ropeC, float* __restrict__ ropeS)
{
    const int NV = (4194304 + 4 * 1048576) / 8;   // 1,048,576 vec8 chunks
    int gid = blockIdx.x * 256 + threadIdx.x;
    for (int i = gid; i < NV; i += gridDim.x * 256) {
        long e = (long)i * 8;
        const float* src; unsigned short* dst; long off;
        if (e < 4194304)      { src = x;  dst = x16;              off = e; }
        else if (e < 5242880) { src = Wq; dst = Wqkv16;           off = e - 4194304; }
        else if (e < 6291456) { src = Wk; dst = Wqkv16 + 1048576; off = e - 5242880; }
        else if (e < 7340032) { src = Wv; dst = Wqkv16 + 2097152; off = e - 6291456; }
        else                  { src = Wo; dst = Wo16;             off = e - 7340032; }
        float4 v0 = *reinterpret_cast<const float4*>(src + off);
        float4 v1 = *reinterpret_cast<const float4*>(src + off + 4);
        u16x8 o;
        o[0] = f16u(v0.x); o[1] = f16u(v0.y); o[2] = f16u(v0.z); o[3] = f16u(v0.w);
        o[4] = f16u(v1.x); o[5] = f16u(v1.y); o[6] = f16u(v1.z); o[7] = f16u(v1.w);
        *reinterpret_cast<u16x8*>(dst + off) = o;
    }
    if (gid < 65536) {
        int npos = gid >> 5, j = gid & 31;
        float f = (float)npos * rope_theta(j);
        ropeC[gid] = cosf(f);
        ropeS[gid] = sinf(f);
    }
    if (gid < 3072) {
        biasqkv[gid] = gid < 1024 ? bq[gid] : (gid < 2048 ? bk[gid - 1024] : bv[gid - 2048]);
    }
}

// ---------------------------------------------------------------------------
// Fused QKV GEMM + bias + (non-standard) rope. 512 thr / 8 waves (64x32
// sub-tiles), double-buffered swizzled LDS, 1 barrier per K-step.
//   Q, K -> (b,h,n,d) f16;  V -> TRANSPOSED (b,h,d,n) f16 via LDS transpose.
//   out[p]    = x[2p]*rope[2p]   - x[2p+1]*rope[2p+1]
//   out[p+32] = x[2p]*rope[2p+1] + x[2p+1]*rope[2p]
// LDS: buf{0,1} = {As 16KB | Bs 16KB}; T[128][136] aliases buf0 at end.
// ---------------------------------------------------------------------------
__global__ __launch_bounds__(512, 4) void qkv_gemm_kernel(
    const unsigned short* __restrict__ A, const unsigned short* __restrict__ B,
    const float* __restrict__ bias, const float* __restrict__ ropeC,
    const float* __restrict__ ropeS, unsigned short* __restrict__ QKV)
{
    __shared__ __align__(16) unsigned char smem[65536];
    const int tid = threadIdx.x;
    const int w = tid >> 6, l = tid & 63;
    const int g = l >> 4, lx = l & 15;
    const int wr = w >> 2, wc = w & 3;        // 2x4 wave grid: 64x32 subtile
    const int row0 = blockIdx.y * 128;
    const int col0 = blockIdx.x * 128;
    const unsigned short* Ab = A + (size_t)row0 * DIMSZ;
    const unsigned short* Bb = B + (size_t)col0 * DIMSZ;

    // staging map: instr i covers rows i*64 + (tid>>3), chunk tid&7 (swizzled)
    const int sr = tid >> 3;                   // 0..63
    const int sc = tid & 7;
    const int ssw = sc ^ (sr & 7);             // row&7 == sr&7 for both instr
    const size_t sAoff0 = (size_t)sr * DIMSZ + ssw * 8;
    const size_t sAoff1 = (size_t)(64 + sr) * DIMSZ + ssw * 8;

    f32x4 acc[4][2] = {};
    // ---- prologue: stage K-tile 0 into buf 0
    async_copy16(Ab + sAoff0, smem + tid * 16);
    async_copy16(Ab + sAoff1, smem + 8192 + tid * 16);
    async_copy16(Bb + sAoff0, smem + 16384 + tid * 16);
    async_copy16(Bb + sAoff1, smem + 16384 + 8192 + tid * 16);
    __syncthreads();

    int buf = 0;
    for (int k0 = 0; k0 < DIMSZ; k0 += 64) {
        if (k0 + 64 < DIMSZ) {
            const int nb = (buf ^ 1) * 32768;
            async_copy16(Ab + sAoff0 + k0 + 64, smem + nb + tid * 16);
            async_copy16(Ab + sAoff1 + k0 + 64, smem + nb + 8192 + tid * 16);
            async_copy16(Bb + sAoff0 + k0 + 64, smem + nb + 16384 + tid * 16);
            async_copy16(Bb + sAoff1 + k0 + 64, smem + nb + 16384 + 8192 + tid * 16);
        }
        const int ab = buf * 32768, bb2 = ab + 16384;
        #pragma unroll
        for (int ks = 0; ks < 2; ++ks) {
            f16x8 af[4], bf[2];
            #pragma unroll
            for (int m = 0; m < 4; ++m) {
                int r = wr * 64 + m * 16 + lx;
                af[m] = *reinterpret_cast<const f16x8*>(
                    &smem[ab + r * 128 + ((ks * 64 + g * 16) ^ ((r & 7) << 4))]);
            }
            #pragma unroll
            for (int n = 0; n < 2; ++n) {
                int r = wc * 32 + n * 16 + lx;
                bf[n] = *reinterpret_cast<const f16x8*>(
                    &smem[bb2 + r * 128 + ((ks * 64 + g * 16) ^ ((r & 7) << 4))]);
            }
            #pragma unroll
            for (int m = 0; m < 4; ++m)
                #pragma unroll
                for (int n = 0; n < 2; ++n)
                    acc[m][n] = __builtin_amdgcn_mfma_f32_16x16x32_f16(af[m], bf[n], acc[m][n], 0, 0, 0);
        }
        __syncthreads();
        buf ^= 1;
    }

    const int proj = col0 >> 10;               // block-uniform
    const int cin128 = (col0 & 1023);          // head base within proj (mult of 128)
    float bsv[2];
    #pragma unroll
    for (int n = 0; n < 2; ++n) bsv[n] = bias[col0 + wc * 32 + n * 16 + lx];

    if (proj == 2) {
        // ---- V: rope -> LDS transpose T[trow][rlocal] -> coalesced (b,h,d,n)
        _Float16* T = (_Float16*)smem;   // [128][136] = 34816B (aliases bufs)
        #pragma unroll
        for (int m = 0; m < 4; ++m) {
            int rl0 = wr * 64 + m * 16 + g * 4;
            #pragma unroll
            for (int r2 = 0; r2 < 4; ++r2) {
                int rlocal = rl0 + r2;
                int npos = (row0 + rlocal) & (SEQLEN - 1);
                const float* rcp = ropeC + npos * 32;
                const float* rsp = ropeS + npos * 32;
                #pragma unroll
                for (int n = 0; n < 2; ++n) {
                    float v = acc[m][n][r2] + bsv[n];
                    float o = __shfl_xor(v, 1);
                    int dcol = wc * 32 + n * 16 + lx;      // 0..127
                    int c = dcol & 63;                      // head-local col
                    const float* tab = (c < 32) ? rcp : rsp;
                    float Rd = tab[c & 31];
                    float Rp = tab[(c & 31) ^ 1];
                    float y; int outc;
                    if (c & 1) { y = o * Rd + v * Rp; outc = (c >> 1) + 32; }
                    else       { y = v * Rd - o * Rp; outc = c >> 1; }
                    T[((dcol >> 6) * 64 + outc) * 136 + rlocal] = (_Float16)y;
                }
            }
        }
        __syncthreads();
        int b = row0 >> 11, npos0 = row0 & (SEQLEN - 1);
        int hd0 = cin128 >> 6;
        int trow = tid >> 2;                    // 0..127
        int cbase = (tid & 3) * 32;
        int head = hd0 + (trow >> 6);
        int outd = trow & 63;
        unsigned short* vdst = QKV + 8388608 +
            (((size_t)b * NHEADS + head) * HDIM + outd) * SEQLEN + npos0 + cbase;
        #pragma unroll
        for (int i2 = 0; i2 < 4; ++i2) {
            f16x8 val = *reinterpret_cast<const f16x8*>(&T[trow * 136 + cbase + i2 * 8]);
            *reinterpret_cast<f16x8*>(vdst + i2 * 8) = val;
        }
    } else {
        #pragma unroll
        for (int m = 0; m < 4; ++m) {
            int rbase = row0 + wr * 64 + m * 16 + g * 4;
            #pragma unroll
            for (int r2 = 0; r2 < 4; ++r2) {
                int rglob = rbase + r2;
                int b = rglob >> 11, npos = rglob & (SEQLEN - 1);
                const float* rcp = ropeC + npos * 32;
                const float* rsp = ropeS + npos * 32;
                #pragma unroll
                for (int n = 0; n < 2; ++n) {
                    float v = acc[m][n][r2] + bsv[n];
                    float o = __shfl_xor(v, 1);
                    int hd = (cin128 + wc * 32 + n * 16) >> 6;
                    int c = ((wc * 32 + n * 16) & 63) + lx;
                    const float* tab = (c < 32) ? rcp : rsp;
                    float Rd = tab[c & 31];
                    float Rp = tab[(c & 31) ^ 1];
                    float y; int outc;
                    if (c & 1) { y = o * Rd + v * Rp; outc = (c >> 1) + 32; }
                    else       { y = v * Rd - o * Rp; outc = c >> 1; }
                    unsigned short* Orow = QKV +
                        ((((size_t)proj * BATCH + b) * NHEADS + hd) * SEQLEN + npos) * HDIM;
                    Orow[outc] = f16u(y);
                }
            }
        }
    }
}

// ---------------------------------------------------------------------------
// MFMA flash attention (f16), 8 waves = 4 q-groups x 2 KEY-HALVES.
// Swapped QK^T, reg-resident P, K=16 PV, dbuf staging, flash-merge of halves.
// ---------------------------------------------------------------------------
__global__ __launch_bounds__(512, 8) void attn_mfma_kernel(
    const unsigned short* __restrict__ QKV, const float* __restrict__ ropeC,
    const float* __restrict__ ropeS, unsigned short* __restrict__ Y)
{
    __shared__ __align__(16) unsigned char smem[32768];
    const int tid = threadIdx.x;
    const int w   = tid >> 6;
    const int l   = tid & 63;
    const int g   = l >> 4;
    const int lx  = l & 15;
    const int qg  = w & 3;      // q-group: 16 q per wave
    const int kh  = w >> 2;     // key half: 0 -> keys 0..31, 1 -> keys 32..63
    const int fb  = blockIdx.x;
    const int xcd = fb & 7, jj = fb >> 3;
    const int bh  = xcd * 4 + (jj & 3);       // 4 bh per XCD -> K/V L2-local
    const int b   = bh >> 4;
    const int h   = bh & 15;
    const int q0  = (jj >> 2) * 64;

    const unsigned short* Qb  = QKV + (size_t)bh * SEQLEN * HDIM;
    const unsigned short* Kb  = QKV + 4194304 + (size_t)bh * SEQLEN * HDIM;
    const unsigned short* Vtb = QKV + 8388608 + (size_t)bh * SEQLEN * HDIM;  // (d,n)

    f16x8 qf[2];
    {
        const unsigned short* src = Qb + (size_t)(q0 + qg * 16 + lx) * HDIM + g * 8;
        qf[0] = *reinterpret_cast<const f16x8*>(src);
        qf[1] = *reinterpret_cast<const f16x8*>(src + 32);
    }
    f16x4 ones4;
    #pragma unroll
    for (int i = 0; i < 4; ++i) ones4[i] = (_Float16)1.0f;

    const float K2 = 0.18033688011112043f;    // 0.125 * log2(e)
    f32x4 oacc[4] = {};                        // O^T partial: d=c2*16+g*4+r, q=lx
    f32x4 lsum = {};
    float mrow = -1e30f;                       // per-lane: one q, this key-half

    const int srow = tid >> 3;                 // 0..63
    const int c8   = tid & 7;
    const int sch  = c8 ^ (srow & 7);
    const int sdst = tid * 16;

    async_copy16(Kb  + (size_t)srow * HDIM + sch * 8, smem + sdst);
    async_copy16(Vtb + (size_t)srow * SEQLEN + sch * 8, smem + 8192 + sdst);
    __syncthreads();

    int buf = 0;
    for (int kt = 0; kt < SEQLEN / 64; ++kt) {
        if (kt + 1 < SEQLEN / 64) {
            const int k0n = (kt + 1) * 64;
            const int nb = (buf ^ 1) * 16384;
            async_copy16(Kb  + (size_t)(k0n + srow) * HDIM + sch * 8,
                         smem + nb + sdst);
            async_copy16(Vtb + (size_t)srow * SEQLEN + k0n + sch * 8,
                         smem + nb + 8192 + sdst);
        }
        const int kb = buf * 16384;
        const int vb = kb + 8192;

        f32x4 sacc[2] = {};
        __builtin_amdgcn_s_setprio(1);
        #pragma unroll
        for (int c = 0; c < 2; ++c) {
            int key = kh * 32 + c * 16 + lx;
            int rowb = kb + key * 128, sw = (key & 7) << 4;
            f16x8 k0f = *reinterpret_cast<const f16x8*>(&smem[rowb + ((g * 16) ^ sw)]);
            f16x8 k1f = *reinterpret_cast<const f16x8*>(&smem[rowb + ((64 + g * 16) ^ sw)]);
            sacc[c] = __builtin_amdgcn_mfma_f32_16x16x32_f16(k0f, qf[0], sacc[c], 0, 0, 0);
            sacc[c] = __builtin_amdgcn_mfma_f32_16x16x32_f16(k1f, qf[1], sacc[c], 0, 0, 0);
        }
        __builtin_amdgcn_s_setprio(0);

        float lmax = sacc[0][0];
        #pragma unroll
        for (int c = 0; c < 2; ++c)
            #pragma unroll
            for (int r = 0; r < 4; ++r) lmax = fmaxf(lmax, sacc[c][r]);
        bool ok = (lmax <= mrow + 64.f);
        if (!__all((int)ok)) {
            float m2 = fmaxf(lmax, __shfl_xor(lmax, 16));
            m2 = fmaxf(m2, __shfl_xor(m2, 32));
            float mnew = fmaxf(mrow, m2);
            float sc = exp2f((mrow - mnew) * K2);
            mrow = mnew;
            #pragma unroll
            for (int r = 0; r < 4; ++r) lsum[r] *= sc;
            #pragma unroll
            for (int c = 0; c < 4; ++c)
                #pragma unroll
                for (int r = 0; r < 4; ++r) oacc[c][r] *= sc;
        }
        float mk = -mrow * K2;
        #pragma unroll
        for (int c = 0; c < 2; ++c)
            #pragma unroll
            for (int r = 0; r < 4; ++r)
                sacc[c][r] = exp2f(fmaf(sacc[c][r], K2, mk));

        #pragma unroll
        for (int c = 0; c < 2; ++c) {
            unsigned p0 = __builtin_bit_cast(unsigned,
                __builtin_amdgcn_cvt_pkrtz(sacc[c][0], sacc[c][1]));
            unsigned p1 = __builtin_bit_cast(unsigned,
                __builtin_amdgcn_cvt_pkrtz(sacc[c][2], sacc[c][3]));
            u32x2 pw = { p0, p1 };
            f16x4 pfrag = __builtin_bit_cast(f16x4, pw);
            __builtin_amdgcn_s_setprio(1);
            lsum = __builtin_amdgcn_mfma_f32_16x16x16f16(ones4, pfrag, lsum, 0, 0, 0);
            #pragma unroll
            for (int c2 = 0; c2 < 4; ++c2) {
                int d = c2 * 16 + lx;
                int off = kh * 64 + c * 32 + g * 8;
                f16x4 vf4 = *reinterpret_cast<const f16x4*>(
                    &smem[vb + d * 128 + (off ^ ((d & 7) << 4))]);
                oacc[c2] = __builtin_amdgcn_mfma_f32_16x16x16f16(vf4, pfrag, oacc[c2], 0, 0, 0);
            }
            __builtin_amdgcn_s_setprio(0);
        }

        __syncthreads();
        buf ^= 1;
    }

    // ---- key-half merge via LDS (flash-merge), then -rope epilogue
    float* Of = (float*)smem + qg * 1120;
    if (kh == 1) {
        #pragma unroll
        for (int c2 = 0; c2 < 4; ++c2)
            *reinterpret_cast<f32x4*>(&Of[lx * 68 + c2 * 16 + g * 4]) = oacc[c2];
        if (g == 0) {
            Of[1088 + lx] = mrow;
            Of[1104 + lx] = lsum[0];
        }
    }
    __syncthreads();
    if (kh == 0) {
        float m_hi = Of[1088 + lx];
        float l_hi = Of[1104 + lx];
        float M = fmaxf(mrow, m_hi);
        float a  = exp2f((mrow - M) * K2);
        float bb = exp2f((m_hi - M) * K2);
        float inv = 1.0f / (a * lsum[0] + bb * l_hi);
        const int q = q0 + qg * 16 + lx;
        unsigned short* drow = Y + ((size_t)b * SEQLEN + q) * DIMSZ + h * HDIM;
        #pragma unroll
        for (int c2 = 0; c2 < 4; ++c2) {
            f32x4 ohi = *reinterpret_cast<const f32x4*>(&Of[lx * 68 + c2 * 16 + g * 4]);
            const float* tab = ((c2 < 2) ? ropeC : ropeS) + (size_t)q * 32;
            unsigned short lo16[2], hi16[2];
            #pragma unroll
            for (int rp = 0; rp < 2; ++rp) {
                int d = c2 * 16 + g * 4 + 2 * rp;        // even d
                float v0 = (a * oacc[c2][2 * rp]     + bb * ohi[2 * rp])     * inv;
                float v1 = (a * oacc[c2][2 * rp + 1] + bb * ohi[2 * rp + 1]) * inv;
                float Rd = tab[d & 31], Rn = tab[(d & 31) + 1];
                lo16[rp] = f16u(-(v0 * Rd - v1 * Rn));
                hi16[rp] = f16u(-(v0 * Rn + v1 * Rd));
            }
            int p = c2 * 8 + g * 2;                       // even column
            *reinterpret_cast<unsigned*>(&drow[p])      = (unsigned)lo16[0] | ((unsigned)lo16[1] << 16);
            *reinterpret_cast<unsigned*>(&drow[p + 32]) = (unsigned)hi16[0] | ((unsigned)hi16[1] << 16);
        }
    }
}

// ---------------------------------------------------------------------------
// Out GEMM: out[4096 x 1024] = Y16 @ Wo16^T + bo (f32 out).
// Same 512-thr / 8-wave dbuf swizzled structure as qkv_gemm.
// ---------------------------------------------------------------------------
__global__ __launch_bounds__(512, 4) void out_gemm_kernel(
    const unsigned short* __restrict__ A, const unsigned short* __restrict__ B,
    const float* __restrict__ bias, float* __restrict__ Out)
{
    __shared__ __align__(16) unsigned char smem[65536];
    const int tid = threadIdx.x;
    const int w = tid >> 6, l = tid & 63;
    const int g = l >> 4, lx = l & 15;
    const int wr = w >> 2, wc = w & 3;
    const int row0 = blockIdx.y * 128;
    const int col0 = blockIdx.x * 128;
    const unsigned short* Ab = A + (size_t)row0 * DIMSZ;
    const unsigned short* Bb = B + (size_t)col0 * DIMSZ;

    const int sr = tid >> 3;
    const int sc = tid & 7;
    const int ssw = sc ^ (sr & 7);
    const size_t sAoff0 = (size_t)sr * DIMSZ + ssw * 8;
    const size_t sAoff1 = (size_t)(64 + sr) * DIMSZ + ssw * 8;

    f32x4 acc[4][2] = {};
    async_copy16(Ab + sAoff0, smem + tid * 16);
    async_copy16(Ab + sAoff1, smem + 8192 + tid * 16);
    async_copy16(Bb + sAoff0, smem + 16384 + tid * 16);
    async_copy16(Bb + sAoff1, smem + 16384 + 8192 + tid * 16);
    __syncthreads();

    int buf = 0;
    for (int k0 = 0; k0 < DIMSZ; k0 += 64) {
        if (k0 + 64 < DIMSZ) {
            const int nb = (buf ^ 1) * 32768;
            async_copy16(Ab + sAoff0 + k0 + 64, smem + nb + tid * 16);
            async_copy16(Ab + sAoff1 + k0 + 64, smem + nb + 8192 + tid * 16);
            async_copy16(Bb + sAoff0 + k0 + 64, smem + nb + 16384 + tid * 16);
            async_copy16(Bb + sAoff1 + k0 + 64, smem + nb + 16384 + 8192 + tid * 16);
        }
        const int ab = buf * 32768, bb2 = ab + 16384;
        #pragma unroll
        for (int ks = 0; ks < 2; ++ks) {
            f16x8 af[4], bf[2];
            #pragma unroll
            for (int m = 0; m < 4; ++m) {
                int r = wr * 64 + m * 16 + lx;
                af[m] = *reinterpret_cast<const f16x8*>(
                    &smem[ab + r * 128 + ((ks * 64 + g * 16) ^ ((r & 7) << 4))]);
            }
            #pragma unroll
            for (int n = 0; n < 2; ++n) {
                int r = wc * 32 + n * 16 + lx;
                bf[n] = *reinterpret_cast<const f16x8*>(
                    &smem[bb2 + r * 128 + ((ks * 64 + g * 16) ^ ((r & 7) << 4))]);
            }
            #pragma unroll
            for (int m = 0; m < 4; ++m)
                #pragma unroll
                for (int n = 0; n < 2; ++n)
                    acc[m][n] = __builtin_amdgcn_mfma_f32_16x16x32_f16(af[m], bf[n], acc[m][n], 0, 0, 0);
        }
        __syncthreads();
        buf ^= 1;
    }

    const int cb0 = col0 + wc * 32;
    float bsv[2];
    #pragma unroll
    for (int n = 0; n < 2; ++n) bsv[n] = bias[cb0 + n * 16 + lx];
    #pragma unroll
    for (int m = 0; m < 4; ++m) {
        int rbase = row0 + wr * 64 + m * 16 + g * 4;
        #pragma unroll
        for (int r2 = 0; r2 < 4; ++r2) {
            float* orow = Out + (size_t)(rbase + r2) * DIMSZ + cb0;
            #pragma unroll
            for (int n = 0; n < 2; ++n)
                orow[n * 16 + lx] = acc[m][n][r2] + bsv[n];
        }
    }
}

extern "C" void kernel_launch(void* const* d_in, const int* in_sizes, int n_in,
                              void* d_out, int out_size, void* d_ws, size_t ws_size,
                              hipStream_t stream) {
    const float* x  = (const float*)d_in[0];
    const float* Wq = (const float*)d_in[1];
    const float* bq = (const float*)d_in[2];
    const float* Wk = (const float*)d_in[3];
    const float* bk = (const float*)d_in[4];
    const float* Wv = (const float*)d_in[5];
    const float* bv = (const float*)d_in[6];
    const float* Wo = (const float*)d_in[7];
    const float* bo = (const float*)d_in[8];
    float* out = (float*)d_out;

    char* ws = (char*)d_ws;
    unsigned short* x16    = (unsigned short*)(ws);
    unsigned short* Wqkv16 = (unsigned short*)(ws + 8388608);
    unsigned short* Wo16   = (unsigned short*)(ws + 14680064);
    float* biasqkv         = (float*)(ws + 16777216);
    float* ropeC           = (float*)(ws + 16793600);
    float* ropeS           = (float*)(ws + 17055744);
    unsigned short* QKVw   = (unsigned short*)(ws + 17825792);
    unsigned short* Yw     = (unsigned short*)(ws + 42991616);

    prep_kernel<<<dim3(2048), dim3(256), 0, stream>>>(x, Wq, Wk, Wv, Wo, bq, bk, bv,
                                                x16, Wqkv16, Wo16, biasqkv, ropeC, ropeS);
    qkv_gemm_kernel<<<dim3(24, 32), dim3(512), 0, stream>>>(x16, Wqkv16, biasqkv, ropeC, ropeS, QKVw);
    attn_mfma_kernel<<<dim3(1024), dim3(512), 0, stream>>>(QKVw, ropeC, ropeS, Yw);
    out_gemm_kernel<<<dim3(8, 32), dim3(512), 0, stream>>>(Yw, Wo16, bo, out);
}

// Round 14
// 135.283 us; speedup vs baseline: 1.3840x; 1.0391x over previous
//
#include <hip/hip_runtime.h>
#include <hip/hip_bf16.h>
#include <math.h>

#define NHEADS 16
#define HDIM   64
#define BATCH  2
#define SEQLEN 2048
#define DIMSZ  1024

typedef _Float16 f16x8 __attribute__((ext_vector_type(8)));
typedef _Float16 f16x4 __attribute__((ext_vector_type(4)));
typedef float    f32x4 __attribute__((ext_vector_type(4)));
typedef unsigned short u16x8 __attribute__((ext_vector_type(8)));
typedef unsigned int   u32x4 __attribute__((ext_vector_type(4)));

__device__ __forceinline__ float rope_theta(int c) {
    int i = c & 31;
    return (float)pow(10000.0, -(double)i / 32.0);
}
__device__ __forceinline__ unsigned short f16u(float f) {
    _Float16 h = (_Float16)f;
    return *reinterpret_cast<unsigned short*>(&h);
}
__device__ __forceinline__ void async_copy16(const void* gsrc, void* lds) {
    __builtin_amdgcn_global_load_lds(
        (const __attribute__((address_space(1))) unsigned int*)gsrc,
        (__attribute__((address_space(3))) unsigned int*)lds, 16, 0, 0);
}

// ---------------------------------------------------------------------------
// prep: f32->f16 conversions (x, Wq|Wk|Wv concat, Wo), bias concat, rope tables
// ---------------------------------------------------------------------------
__global__ __launch_bounds__(256) void prep_kernel(
    const float* __restrict__ x, const float* __restrict__ Wq,
    const float* __restrict__ Wk, const float* __restrict__ Wv,
    const float* __restrict__ Wo, const float* __restrict__ bq,
    const float* __restrict__ bk, const float* __restrict__ bv,
    unsigned short* __restrict__ x16, unsigned short* __restrict__ Wqkv16,
    unsigned short* __restrict__ Wo16, float* __restrict__ biasqkv,
    float* __restrict__ ropeC, float* __restrict__ ropeS)
{
    const int NV = (4194304 + 4 * 1048576) / 8;   // 1,048,576 vec8 chunks
    int gid = blockIdx.x * 256 + threadIdx.x;
    for (int i = gid; i < NV; i += gridDim.x * 256) {
        long e = (long)i * 8;
        const float* src; unsigned short* dst; long off;
        if (e < 4194304)      { src = x;  dst = x16;              off = e; }
        else if (e < 5242880) { src = Wq; dst = Wqkv16;           off = e - 4194304; }
        else if (e < 6291456) { src = Wk; dst = Wqkv16 + 1048576; off = e - 5242880; }
        else if (e < 7340032) { src = Wv; dst = Wqkv16 + 2097152; off = e - 6291456; }
        else                  { src = Wo; dst = Wo16;             off = e - 7340032; }
        float4 v0 = *reinterpret_cast<const float4*>(src + off);
        float4 v1 = *reinterpret_cast<const float4*>(src + off + 4);
        u16x8 o;
        o[0] = f16u(v0.x); o[1] = f16u(v0.y); o[2] = f16u(v0.z); o[3] = f16u(v0.w);
        o[4] = f16u(v1.x); o[5] = f16u(v1.y); o[6] = f16u(v1.z); o[7] = f16u(v1.w);
        *reinterpret_cast<u16x8*>(dst + off) = o;
    }
    if (gid < 65536) {
        int npos = gid >> 5, j = gid & 31;
        float f = (float)npos * rope_theta(j);
        ropeC[gid] = cosf(f);
        ropeS[gid] = sinf(f);
    }
    if (gid < 3072) {
        biasqkv[gid] = gid < 1024 ? bq[gid] : (gid < 2048 ? bk[gid - 1024] : bv[gid - 2048]);
    }
}

// ---------------------------------------------------------------------------
// Fused QKV GEMM + bias + (non-standard) rope. 512 thr / 8 waves (64x32
// sub-tiles), double-buffered swizzled LDS, 1 barrier per K-step.
// ---------------------------------------------------------------------------
__global__ __launch_bounds__(512, 4) void qkv_gemm_kernel(
    const unsigned short* __restrict__ A, const unsigned short* __restrict__ B,
    const float* __restrict__ bias, const float* __restrict__ ropeC,
    const float* __restrict__ ropeS, unsigned short* __restrict__ QKV)
{
    __shared__ __align__(16) unsigned char smem[65536];
    const int tid = threadIdx.x;
    const int w = tid >> 6, l = tid & 63;
    const int g = l >> 4, lx = l & 15;
    const int wr = w >> 2, wc = w & 3;        // 2x4 wave grid: 64x32 subtile
    const int row0 = blockIdx.y * 128;
    const int col0 = blockIdx.x * 128;
    const unsigned short* Ab = A + (size_t)row0 * DIMSZ;
    const unsigned short* Bb = B + (size_t)col0 * DIMSZ;

    const int sr = tid >> 3;                   // 0..63
    const int sc = tid & 7;
    const int ssw = sc ^ (sr & 7);
    const size_t sAoff0 = (size_t)sr * DIMSZ + ssw * 8;
    const size_t sAoff1 = (size_t)(64 + sr) * DIMSZ + ssw * 8;

    f32x4 acc[4][2] = {};
    async_copy16(Ab + sAoff0, smem + tid * 16);
    async_copy16(Ab + sAoff1, smem + 8192 + tid * 16);
    async_copy16(Bb + sAoff0, smem + 16384 + tid * 16);
    async_copy16(Bb + sAoff1, smem + 16384 + 8192 + tid * 16);
    __syncthreads();

    int buf = 0;
    for (int k0 = 0; k0 < DIMSZ; k0 += 64) {
        if (k0 + 64 < DIMSZ) {
            const int nb = (buf ^ 1) * 32768;
            async_copy16(Ab + sAoff0 + k0 + 64, smem + nb + tid * 16);
            async_copy16(Ab + sAoff1 + k0 + 64, smem + nb + 8192 + tid * 16);
            async_copy16(Bb + sAoff0 + k0 + 64, smem + nb + 16384 + tid * 16);
            async_copy16(Bb + sAoff1 + k0 + 64, smem + nb + 16384 + 8192 + tid * 16);
        }
        const int ab = buf * 32768, bb2 = ab + 16384;
        #pragma unroll
        for (int ks = 0; ks < 2; ++ks) {
            f16x8 af[4], bf[2];
            #pragma unroll
            for (int m = 0; m < 4; ++m) {
                int r = wr * 64 + m * 16 + lx;
                af[m] = *reinterpret_cast<const f16x8*>(
                    &smem[ab + r * 128 + ((ks * 64 + g * 16) ^ ((r & 7) << 4))]);
            }
            #pragma unroll
            for (int n = 0; n < 2; ++n) {
                int r = wc * 32 + n * 16 + lx;
                bf[n] = *reinterpret_cast<const f16x8*>(
                    &smem[bb2 + r * 128 + ((ks * 64 + g * 16) ^ ((r & 7) << 4))]);
            }
            #pragma unroll
            for (int m = 0; m < 4; ++m)
                #pragma unroll
                for (int n = 0; n < 2; ++n)
                    acc[m][n] = __builtin_amdgcn_mfma_f32_16x16x32_f16(af[m], bf[n], acc[m][n], 0, 0, 0);
        }
        __syncthreads();
        buf ^= 1;
    }

    const int proj = col0 >> 10;               // block-uniform
    const int cin128 = (col0 & 1023);
    float bsv[2];
    #pragma unroll
    for (int n = 0; n < 2; ++n) bsv[n] = bias[col0 + wc * 32 + n * 16 + lx];

    if (proj == 2) {
        _Float16* T = (_Float16*)smem;   // [128][136]
        #pragma unroll
        for (int m = 0; m < 4; ++m) {
            int rl0 = wr * 64 + m * 16 + g * 4;
            #pragma unroll
            for (int r2 = 0; r2 < 4; ++r2) {
                int rlocal = rl0 + r2;
                int npos = (row0 + rlocal) & (SEQLEN - 1);
                const float* rcp = ropeC + npos * 32;
                const float* rsp = ropeS + npos * 32;
                #pragma unroll
                for (int n = 0; n < 2; ++n) {
                    float v = acc[m][n][r2] + bsv[n];
                    float o = __shfl_xor(v, 1);
                    int dcol = wc * 32 + n * 16 + lx;
                    int c = dcol & 63;
                    const float* tab = (c < 32) ? rcp : rsp;
                    float Rd = tab[c & 31];
                    float Rp = tab[(c & 31) ^ 1];
                    float y; int outc;
                    if (c & 1) { y = o * Rd + v * Rp; outc = (c >> 1) + 32; }
                    else       { y = v * Rd - o * Rp; outc = c >> 1; }
                    T[((dcol >> 6) * 64 + outc) * 136 + rlocal] = (_Float16)y;
                }
            }
        }
        __syncthreads();
        int b = row0 >> 11, npos0 = row0 & (SEQLEN - 1);
        int hd0 = cin128 >> 6;
        int trow = tid >> 2;
        int cbase = (tid & 3) * 32;
        int head = hd0 + (trow >> 6);
        int outd = trow & 63;
        unsigned short* vdst = QKV + 8388608 +
            (((size_t)b * NHEADS + head) * HDIM + outd) * SEQLEN + npos0 + cbase;
        #pragma unroll
        for (int i2 = 0; i2 < 4; ++i2) {
            f16x8 val = *reinterpret_cast<const f16x8*>(&T[trow * 136 + cbase + i2 * 8]);
            *reinterpret_cast<f16x8*>(vdst + i2 * 8) = val;
        }
    } else {
        #pragma unroll
        for (int m = 0; m < 4; ++m) {
            int rbase = row0 + wr * 64 + m * 16 + g * 4;
            #pragma unroll
            for (int r2 = 0; r2 < 4; ++r2) {
                int rglob = rbase + r2;
                int b = rglob >> 11, npos = rglob & (SEQLEN - 1);
                const float* rcp = ropeC + npos * 32;
                const float* rsp = ropeS + npos * 32;
                #pragma unroll
                for (int n = 0; n < 2; ++n) {
                    float v = acc[m][n][r2] + bsv[n];
                    float o = __shfl_xor(v, 1);
                    int hd = (cin128 + wc * 32 + n * 16) >> 6;
                    int c = ((wc * 32 + n * 16) & 63) + lx;
                    const float* tab = (c < 32) ? rcp : rsp;
                    float Rd = tab[c & 31];
                    float Rp = tab[(c & 31) ^ 1];
                    float y; int outc;
                    if (c & 1) { y = o * Rd + v * Rp; outc = (c >> 1) + 32; }
                    else       { y = v * Rd - o * Rp; outc = c >> 1; }
                    unsigned short* Orow = QKV +
                        ((((size_t)proj * BATCH + b) * NHEADS + hd) * SEQLEN + npos) * HDIM;
                    Orow[outc] = f16u(y);
                }
            }
        }
    }
}

// ---------------------------------------------------------------------------
// MFMA flash attention (f16), 8 waves = 4 q-groups x 2 key-halves.
// K staged with PERMUTED row order: LDS row hh*32 + c*16 + g*4 + r holds key
// hh*32 + g*8 + c*4 + r.  Then sacc[c][r] = key g*8+c*4+r, so the packed P
// registers {pk0,pk1,pk2,pk3} form the K=32 MFMA B-fragment directly
// (k = g*8+j), PV uses b128 V^T reads (conflict-free), zero cross-lane ops.
// Flash-merge of key-half partials at the end.
// ---------------------------------------------------------------------------
__global__ __launch_bounds__(512, 8) void attn_mfma_kernel(
    const unsigned short* __restrict__ QKV, const float* __restrict__ ropeC,
    const float* __restrict__ ropeS, unsigned short* __restrict__ Y)
{
    __shared__ __align__(16) unsigned char smem[32768];
    const int tid = threadIdx.x;
    const int w   = tid >> 6;
    const int l   = tid & 63;
    const int g   = l >> 4;
    const int lx  = l & 15;
    const int qg  = w & 3;      // q-group: 16 q per wave
    const int kh  = w >> 2;     // key half: 0 -> keys 0..31, 1 -> keys 32..63
    const int fb  = blockIdx.x;
    const int xcd = fb & 7, jj = fb >> 3;
    const int bh  = xcd * 4 + (jj & 3);       // 4 bh per XCD -> K/V L2-local
    const int b   = bh >> 4;
    const int h   = bh & 15;
    const int q0  = (jj >> 2) * 64;

    const unsigned short* Qb  = QKV + (size_t)bh * SEQLEN * HDIM;
    const unsigned short* Kb  = QKV + 4194304 + (size_t)bh * SEQLEN * HDIM;
    const unsigned short* Vtb = QKV + 8388608 + (size_t)bh * SEQLEN * HDIM;  // (d,n)

    f16x8 qf[2];
    {
        const unsigned short* src = Qb + (size_t)(q0 + qg * 16 + lx) * HDIM + g * 8;
        qf[0] = *reinterpret_cast<const f16x8*>(src);
        qf[1] = *reinterpret_cast<const f16x8*>(src + 32);
    }
    f16x8 ones8;
    #pragma unroll
    for (int i = 0; i < 8; ++i) ones8[i] = (_Float16)1.0f;

    const float K2 = 0.18033688011112043f;    // 0.125 * log2(e)
    f32x4 oacc[4] = {};                        // O^T partial: d=c2*16+g*4+r, q=lx
    f32x4 lsum = {};
    float mrow = -1e30f;                       // per-lane: one q, this key-half

    // staging: LDS row j holds K key perm(j); V^T rows unpermuted.
    const int srow = tid >> 3;                 // LDS row j = 0..63
    const int c8   = tid & 7;
    const int sch  = c8 ^ (srow & 7);
    const int sdst = tid * 16;
    // perm(j): key = (j&32) + ((j>>2)&3)*8 + ((j>>4)&1)*4 + (j&3)
    const int kperm = (srow & 32) + (((srow >> 2) & 3) << 3) + (((srow >> 4) & 1) << 2) + (srow & 3);

    async_copy16(Kb  + (size_t)kperm * HDIM + sch * 8, smem + sdst);
    async_copy16(Vtb + (size_t)srow * SEQLEN + sch * 8, smem + 8192 + sdst);
    __syncthreads();

    int buf = 0;
    for (int kt = 0; kt < SEQLEN / 64; ++kt) {
        if (kt + 1 < SEQLEN / 64) {
            const int k0n = (kt + 1) * 64;
            const int nb = (buf ^ 1) * 16384;
            async_copy16(Kb  + (size_t)(k0n + kperm) * HDIM + sch * 8,
                         smem + nb + sdst);
            async_copy16(Vtb + (size_t)srow * SEQLEN + k0n + sch * 8,
                         smem + nb + 8192 + sdst);
        }
        const int kb = buf * 16384;
        const int vb = kb + 8192;

        // ---- swapped QK^T: sacc[c][r] = S^T[key kh*32 + g*8 + c*4 + r][q=lx]
        f32x4 sacc[2] = {};
        __builtin_amdgcn_s_setprio(1);
        #pragma unroll
        for (int c = 0; c < 2; ++c) {
            int row = kh * 32 + c * 16 + lx;           // LDS row (permuted keys)
            int rowb = kb + row * 128, sw = (row & 7) << 4;
            f16x8 k0f = *reinterpret_cast<const f16x8*>(&smem[rowb + ((g * 16) ^ sw)]);
            f16x8 k1f = *reinterpret_cast<const f16x8*>(&smem[rowb + ((64 + g * 16) ^ sw)]);
            sacc[c] = __builtin_amdgcn_mfma_f32_16x16x32_f16(k0f, qf[0], sacc[c], 0, 0, 0);
            sacc[c] = __builtin_amdgcn_mfma_f32_16x16x32_f16(k1f, qf[1], sacc[c], 0, 0, 0);
        }
        __builtin_amdgcn_s_setprio(0);

        // ---- softmax, deferred max (THR = 64 raw = 8 post-scale)
        float lmax = sacc[0][0];
        #pragma unroll
        for (int c = 0; c < 2; ++c)
            #pragma unroll
            for (int r = 0; r < 4; ++r) lmax = fmaxf(lmax, sacc[c][r]);
        bool ok = (lmax <= mrow + 64.f);
        if (!__all((int)ok)) {
            float m2 = fmaxf(lmax, __shfl_xor(lmax, 16));
            m2 = fmaxf(m2, __shfl_xor(m2, 32));
            float mnew = fmaxf(mrow, m2);
            float sc = exp2f((mrow - mnew) * K2);
            mrow = mnew;
            #pragma unroll
            for (int r = 0; r < 4; ++r) lsum[r] *= sc;
            #pragma unroll
            for (int c = 0; c < 4; ++c)
                #pragma unroll
                for (int r = 0; r < 4; ++r) oacc[c][r] *= sc;
        }
        float mk = -mrow * K2;
        #pragma unroll
        for (int c = 0; c < 2; ++c)
            #pragma unroll
            for (int r = 0; r < 4; ++r)
                sacc[c][r] = exp2f(fmaf(sacc[c][r], K2, mk));

        // ---- pack P: pfrag8[j] = key kh*32 + g*8 + j  (K=32 B-frag, NO shfl)
        u32x4 pw;
        pw[0] = __builtin_bit_cast(unsigned, __builtin_amdgcn_cvt_pkrtz(sacc[0][0], sacc[0][1]));
        pw[1] = __builtin_bit_cast(unsigned, __builtin_amdgcn_cvt_pkrtz(sacc[0][2], sacc[0][3]));
        pw[2] = __builtin_bit_cast(unsigned, __builtin_amdgcn_cvt_pkrtz(sacc[1][0], sacc[1][1]));
        pw[3] = __builtin_bit_cast(unsigned, __builtin_amdgcn_cvt_pkrtz(sacc[1][2], sacc[1][3]));
        f16x8 pfrag = __builtin_bit_cast(f16x8, pw);

        // ---- PV (K=32) + ones row-sum: b128 conflict-free V^T reads
        __builtin_amdgcn_s_setprio(1);
        lsum = __builtin_amdgcn_mfma_f32_16x16x32_f16(ones8, pfrag, lsum, 0, 0, 0);
        #pragma unroll
        for (int c2 = 0; c2 < 4; ++c2) {
            int d = c2 * 16 + lx;
            f16x8 vf8 = *reinterpret_cast<const f16x8*>(
                &smem[vb + d * 128 + ((kh * 64 + g * 16) ^ ((d & 7) << 4))]);
            oacc[c2] = __builtin_amdgcn_mfma_f32_16x16x32_f16(vf8, pfrag, oacc[c2], 0, 0, 0);
        }
        __builtin_amdgcn_s_setprio(0);

        __syncthreads();
        buf ^= 1;
    }

    // ---- key-half merge via LDS (flash-merge), then -rope epilogue
    float* Of = (float*)smem + qg * 1120;
    if (kh == 1) {
        #pragma unroll
        for (int c2 = 0; c2 < 4; ++c2)
            *reinterpret_cast<f32x4*>(&Of[lx * 68 + c2 * 16 + g * 4]) = oacc[c2];
        if (g == 0) {
            Of[1088 + lx] = mrow;
            Of[1104 + lx] = lsum[0];
        }
    }
    __syncthreads();
    if (kh == 0) {
        float m_hi = Of[1088 + lx];
        float l_hi = Of[1104 + lx];
        float M = fmaxf(mrow, m_hi);
        float a  = exp2f((mrow - M) * K2);
        float bb = exp2f((m_hi - M) * K2);
        float inv = 1.0f / (a * lsum[0] + bb * l_hi);
        const int q = q0 + qg * 16 + lx;
        unsigned short* drow = Y + ((size_t)b * SEQLEN + q) * DIMSZ + h * HDIM;
        #pragma unroll
        for (int c2 = 0; c2 < 4; ++c2) {
            f32x4 ohi = *reinterpret_cast<const f32x4*>(&Of[lx * 68 + c2 * 16 + g * 4]);
            const float* tab = ((c2 < 2) ? ropeC : ropeS) + (size_t)q * 32;
            unsigned short lo16[2], hi16[2];
            #pragma unroll
            for (int rp = 0; rp < 2; ++rp) {
                int d = c2 * 16 + g * 4 + 2 * rp;        // even d
                float v0 = (a * oacc[c2][2 * rp]     + bb * ohi[2 * rp])     * inv;
                float v1 = (a * oacc[c2][2 * rp + 1] + bb * ohi[2 * rp + 1]) * inv;
                float Rd = tab[d & 31], Rn = tab[(d & 31) + 1];
                lo16[rp] = f16u(-(v0 * Rd - v1 * Rn));
                hi16[rp] = f16u(-(v0 * Rn + v1 * Rd));
            }
            int p = c2 * 8 + g * 2;                       // even column
            *reinterpret_cast<unsigned*>(&drow[p])      = (unsigned)lo16[0] | ((unsigned)lo16[1] << 16);
            *reinterpret_cast<unsigned*>(&drow[p + 32]) = (unsigned)hi16[0] | ((unsigned)hi16[1] << 16);
        }
    }
}

// ---------------------------------------------------------------------------
// Out GEMM: out[4096 x 1024] = Y16 @ Wo16^T + bo (f32 out).
// ---------------------------------------------------------------------------
__global__ __launch_bounds__(512, 4) void out_gemm_kernel(
    const unsigned short* __restrict__ A, const unsigned short* __restrict__ B,
    const float* __restrict__ bias, float* __restrict__ Out)
{
    __shared__ __align__(16) unsigned char smem[65536];
    const int tid = threadIdx.x;
    const int w = tid >> 6, l = tid & 63;
    const int g = l >> 4, lx = l & 15;
    const int wr = w >> 2, wc = w & 3;
    const int row0 = blockIdx.y * 128;
    const int col0 = blockIdx.x * 128;
    const unsigned short* Ab = A + (size_t)row0 * DIMSZ;
    const unsigned short* Bb = B + (size_t)col0 * DIMSZ;

    const int sr = tid >> 3;
    const int sc = tid & 7;
    const int ssw = sc ^ (sr & 7);
    const size_t sAoff0 = (size_t)sr * DIMSZ + ssw * 8;
    const size_t sAoff1 = (size_t)(64 + sr) * DIMSZ + ssw * 8;

    f32x4 acc[4][2] = {};
    async_copy16(Ab + sAoff0, smem + tid * 16);
    async_copy16(Ab + sAoff1, smem + 8192 + tid * 16);
    async_copy16(Bb + sAoff0, smem + 16384 + tid * 16);
    async_copy16(Bb + sAoff1, smem + 16384 + 8192 + tid * 16);
    __syncthreads();

    int buf = 0;
    for (int k0 = 0; k0 < DIMSZ; k0 += 64) {
        if (k0 + 64 < DIMSZ) {
            const int nb = (buf ^ 1) * 32768;
            async_copy16(Ab + sAoff0 + k0 + 64, smem + nb + tid * 16);
            async_copy16(Ab + sAoff1 + k0 + 64, smem + nb + 8192 + tid * 16);
            async_copy16(Bb + sAoff0 + k0 + 64, smem + nb + 16384 + tid * 16);
            async_copy16(Bb + sAoff1 + k0 + 64, smem + nb + 16384 + 8192 + tid * 16);
        }
        const int ab = buf * 32768, bb2 = ab + 16384;
        #pragma unroll
        for (int ks = 0; ks < 2; ++ks) {
            f16x8 af[4], bf[2];
            #pragma unroll
            for (int m = 0; m < 4; ++m) {
                int r = wr * 64 + m * 16 + lx;
                af[m] = *reinterpret_cast<const f16x8*>(
                    &smem[ab + r * 128 + ((ks * 64 + g * 16) ^ ((r & 7) << 4))]);
            }
            #pragma unroll
            for (int n = 0; n < 2; ++n) {
                int r = wc * 32 + n * 16 + lx;
                bf[n] = *reinterpret_cast<const f16x8*>(
                    &smem[bb2 + r * 128 + ((ks * 64 + g * 16) ^ ((r & 7) << 4))]);
            }
            #pragma unroll
            for (int m = 0; m < 4; ++m)
                #pragma unroll
                for (int n = 0; n < 2; ++n)
                    acc[m][n] = __builtin_amdgcn_mfma_f32_16x16x32_f16(af[m], bf[n], acc[m][n], 0, 0, 0);
        }
        __syncthreads();
        buf ^= 1;
    }

    const int cb0 = col0 + wc * 32;
    float bsv[2];
    #pragma unroll
    for (int n = 0; n < 2; ++n) bsv[n] = bias[cb0 + n * 16 + lx];
    #pragma unroll
    for (int m = 0; m < 4; ++m) {
        int rbase = row0 + wr * 64 + m * 16 + g * 4;
        #pragma unroll
        for (int r2 = 0; r2 < 4; ++r2) {
            float* orow = Out + (size_t)(rbase + r2) * DIMSZ + cb0;
            #pragma unroll
            for (int n = 0; n < 2; ++n)
                orow[n * 16 + lx] = acc[m][n][r2] + bsv[n];
        }
    }
}

extern "C" void kernel_launch(void* const* d_in, const int* in_sizes, int n_in,
                              void* d_out, int out_size, void* d_ws, size_t ws_size,
                              hipStream_t stream) {
    const float* x  = (const float*)d_in[0];
    const float* Wq = (const float*)d_in[1];
    const float* bq = (const float*)d_in[2];
    const float* Wk = (const float*)d_in[3];
    const float* bk = (const float*)d_in[4];
    const float* Wv = (const float*)d_in[5];
    const float* bv = (const float*)d_in[6];
    const float* Wo = (const float*)d_in[7];
    const float* bo = (const float*)d_in[8];
    float* out = (float*)d_out;

    char* ws = (char*)d_ws;
    unsigned short* x16    = (unsigned short*)(ws);
    unsigned short* Wqkv16 = (unsigned short*)(ws + 8388608);
    unsigned short* Wo16   = (unsigned short*)(ws + 14680064);
    float* biasqkv         = (float*)(ws + 16777216);
    float* ropeC           = (float*)(ws + 16793600);
    float* ropeS           = (float*)(ws + 17055744);
    unsigned short* QKVw   = (unsigned short*)(ws + 17825792);
    unsigned short* Yw     = (unsigned short*)(ws + 42991616);

    prep_kernel<<<dim3(2048), dim3(256), 0, stream>>>(x, Wq, Wk, Wv, Wo, bq, bk, bv,
                                                x16, Wqkv16, Wo16, biasqkv, ropeC, ropeS);
    qkv_gemm_kernel<<<dim3(24, 32), dim3(512), 0, stream>>>(x16, Wqkv16, biasqkv, ropeC, ropeS, QKVw);
    attn_mfma_kernel<<<dim3(1024), dim3(512), 0, stream>>>(QKVw, ropeC, ropeS, Yw);
    out_gemm_kernel<<<dim3(8, 32), dim3(512), 0, stream>>>(Yw, Wo16, bo, out);
}